// Round 10
// baseline (1129.401 us; speedup 1.0000x reference)
//
#include <hip/hip_runtime.h>
#include <hip/hip_bf16.h>

typedef __hip_bfloat16 bf16;
typedef __attribute__((ext_vector_type(8))) short bf16x8;
typedef __attribute__((ext_vector_type(4))) float f32x4;

#define N_NODE   50000
#define N_EDGE   800000
#define N_QUERY  512
#define EPW      8

__device__ __forceinline__ float bfbits2f(unsigned short u) {
    return __uint_as_float(((unsigned)u) << 16);
}
__device__ __forceinline__ unsigned short f2bfbits(float f) {
    unsigned int u = __float_as_uint(f);
    return (unsigned short)((u + 0x7fffu + ((u >> 16) & 1u)) >> 16);  // RNE
}
__device__ __forceinline__ float lrelu(float x) { return x > 0.f ? x : 0.01f * x; }
__device__ __forceinline__ float dot4(float4 a, float4 b, float acc) {
    acc = fmaf(a.x, b.x, acc); acc = fmaf(a.y, b.y, acc);
    acc = fmaf(a.z, b.z, acc); acc = fmaf(a.w, b.w, acc);
    return acc;
}
// async global->LDS DMA: per-lane 4B from per-lane global addr into (base + lane*4)
__device__ __forceinline__ void gld_lds4(const void* g, void* l) {
    __builtin_amdgcn_global_load_lds(
        (const __attribute__((address_space(1))) void*)g,
        (__attribute__((address_space(3))) void*)l, 4, 0, 0);
}
__device__ __forceinline__ void atom_pk_bf16(unsigned int* addr, float a0, float a1) {
    unsigned int old = *((volatile unsigned int*)addr);
    while (true) {
        float f0 = bfbits2f((unsigned short)(old & 0xffffu)) + a0;
        float f1 = bfbits2f((unsigned short)(old >> 16)) + a1;
        unsigned int nv = (unsigned int)f2bfbits(f0) | ((unsigned int)f2bfbits(f1) << 16);
        unsigned int prev = atomicCAS(addr, old, nv);
        if (prev == old) break;
        old = prev;
    }
}

// ---------- dtype detection (pe[0] word: fp32 -> 0x00000000, bf16 -> 0x3F800000) ----------
__global__ void k_detect(const unsigned int* __restrict__ pe_raw, int* __restrict__ flag) {
    *flag = (pe_raw[0] != 0u) ? 1 : 0;   // 1 = bf16 inputs, 0 = fp32 inputs
}

// ---------- zero accumulators (+ sort histogram) ----------
__global__ void k_zero(unsigned int* __restrict__ out_w, int out_elems,
                       const int* __restrict__ flag,
                       float* __restrict__ bot, float* __restrict__ up,
                       int* __restrict__ cnt, int tier_full) {
    int f = *flag;
    int stride = gridDim.x * blockDim.x;
    int tid = blockIdx.x * blockDim.x + threadIdx.x;
    for (int i = tid; i < N_NODE; i += stride) bot[i] = 0.f;
    if (tier_full) {
        for (int i = tid; i < N_NODE * 128; i += stride) up[i] = 0.f;
        for (int i = tid; i < N_NODE + 32; i += stride) cnt[i] = 0;
    } else {
        int out_words = f ? (out_elems >> 1) : out_elems;
        for (int i = tid; i < out_words; i += stride) out_w[i] = 0u;
    }
}

// ---------- counting sort of edges by obj: hist -> scan -> scatter ----------
__global__ void k_hist(const int* __restrict__ edges, int* __restrict__ cnt) {
    int stride = gridDim.x * blockDim.x;
    for (int i = blockIdx.x * blockDim.x + threadIdx.x; i < N_EDGE; i += stride)
        atomicAdd(&cnt[edges[i * 7 + 5]], 1);
}

#define SCAN_T 1024
#define SCAN_C 49   // 1024*49 = 50176 >= N_NODE
__global__ void k_scan(const int* __restrict__ cnt, int* __restrict__ cur) {
    __shared__ int part[SCAN_T];
    int t = threadIdx.x;
    int beg = t * SCAN_C;
    int s = 0;
    for (int i = 0; i < SCAN_C; i++) {
        int idx = beg + i;
        if (idx < N_NODE) s += cnt[idx];
    }
    part[t] = s;
    __syncthreads();
    for (int d = 1; d < SCAN_T; d <<= 1) {
        int v = (t >= d) ? part[t - d] : 0;
        __syncthreads();
        part[t] += v;
        __syncthreads();
    }
    int run = (t == 0) ? 0 : part[t - 1];
    for (int i = 0; i < SCAN_C; i++) {
        int idx = beg + i;
        if (idx < N_NODE) { cur[idx] = run; run += cnt[idx]; }
    }
}

__global__ void k_scat(const int* __restrict__ edges, int* __restrict__ cur,
                       int* __restrict__ perm) {
    int stride = gridDim.x * blockDim.x;
    for (int i = blockIdx.x * blockDim.x + threadIdx.x; i < N_EDGE; i += stride) {
        int obj = edges[i * 7 + 5];
        int pos = atomicAdd(&cur[obj], 1);
        perm[pos] = i;
    }
}

// ---------- convert all small tensors to fp32 pool (transposes W2/Ws/Wr/Wqr) ----------
#define SEG_RELA   51328
#define SEG_PE     32000
#define SEG_W1     20480
#define SEG_B1     128
#define SEG_W2T    16384
#define SEG_B2     128
#define SEG_WST    8192
#define SEG_WS     8192
#define SEG_WRT    8192
#define SEG_WQRT   8192
#define SEG_BQR    64
#define SEG_WA     64
#define SEG_WH     16384
#define POOL_TOTAL (SEG_RELA+SEG_PE+SEG_W1+SEG_B1+SEG_W2T+SEG_B2+SEG_WST+SEG_WS+SEG_WRT+SEG_WQRT+SEG_BQR+SEG_WA+SEG_WH)

__global__ void k_convert(const void* rela, const void* pe, const void* W1, const void* b1,
                          const void* W2, const void* b2, const void* Ws, const void* Wr,
                          const void* Wqr, const void* bqr, const void* walpha, const void* Wh,
                          const int* __restrict__ flag, float* __restrict__ pool) {
    int idx = blockIdx.x * blockDim.x + threadIdx.x;
    int f = *flag;
    auto ld = [&](const void* p, int i) -> float {
        return f ? __bfloat162float(((const bf16*)p)[i]) : ((const float*)p)[i];
    };
    int i = idx;
    if (i < SEG_RELA) { pool[idx] = ld(rela, i); return; } i -= SEG_RELA;
    if (i < SEG_PE)   { pool[idx] = ld(pe, i); return; }   i -= SEG_PE;
    if (i < SEG_W1)   { pool[idx] = ld(W1, i); return; }   i -= SEG_W1;
    if (i < SEG_B1)   { pool[idx] = ld(b1, i); return; }   i -= SEG_B1;
    if (i < SEG_W2T)  { pool[idx] = ld(W2, (i & 127) * 128 + (i >> 7)); return; } i -= SEG_W2T;
    if (i < SEG_B2)   { pool[idx] = ld(b2, i); return; }   i -= SEG_B2;
    if (i < SEG_WST)  { pool[idx] = ld(Ws,  (i & 127) * 64 + (i >> 7)); return; } i -= SEG_WST;
    if (i < SEG_WS)   { pool[idx] = ld(Ws, i); return; }   i -= SEG_WS;
    if (i < SEG_WRT)  { pool[idx] = ld(Wr,  (i & 127) * 64 + (i >> 7)); return; } i -= SEG_WRT;
    if (i < SEG_WQRT) { pool[idx] = ld(Wqr, (i & 127) * 64 + (i >> 7)); return; } i -= SEG_WQRT;
    if (i < SEG_BQR)  { pool[idx] = ld(bqr, i); return; }  i -= SEG_BQR;
    if (i < SEG_WA)   { pool[idx] = ld(walpha, i); return; } i -= SEG_WA;
    if (i < SEG_WH)   { pool[idx] = ld(Wh, i); return; }
}

// ---------- pack W2/Wr into MFMA B-fragment order (bf16) ----------
__global__ void k_pack(const float* __restrict__ W2T_f, const float* __restrict__ WrT_f,
                       short* __restrict__ W2pk, short* __restrict__ Wrpk) {
    int idx = blockIdx.x * blockDim.x + threadIdx.x;
    if (idx < 16384) {
        int j = idx & 7, lane = (idx >> 3) & 63, kb = (idx >> 9) & 3, nt = idx >> 11;
        int k = kb * 32 + (lane >> 4) * 8 + j, n = nt * 16 + (lane & 15);
        W2pk[idx] = (short)f2bfbits(W2T_f[n * 128 + k]);
    } else if (idx < 16384 + 8192) {
        int i2 = idx - 16384;
        int j = i2 & 7, lane = (i2 >> 3) & 63, kb = (i2 >> 9) & 3, nt = i2 >> 11;
        int k = kb * 32 + (lane >> 4) * 8 + j, n = nt * 16 + (lane & 15);
        Wrpk[i2] = (short)f2bfbits(WrT_f[n * 128 + k]);
    }
}

// ---------- precompute tables ----------
__global__ void k_arel(const float* __restrict__ rela_f, const float* __restrict__ W1_f,
                       float* __restrict__ A_rel, unsigned short* __restrict__ relcat) {
    __shared__ float ld[128];
    int r = blockIdx.x, j = threadIdx.x;
    float rv = rela_f[r * 128 + j];
    ld[j] = rv;
    __syncthreads();
    float acc = 0.f;
    for (int k = 0; k < 128; k++) acc = fmaf(ld[k], W1_f[k * 128 + j], acc);
    A_rel[r * 128 + j] = acc;
    relcat[r * 256 + j] = f2bfbits(acc);
    relcat[r * 256 + 128 + j] = f2bfbits(rv);
}

__global__ void k_atime(const float* __restrict__ pe_f, const float* __restrict__ W1_f,
                        const float* __restrict__ b1_f, float* __restrict__ A_timeb,
                        unsigned short* __restrict__ atimb) {
    __shared__ float ld[32];
    int t = blockIdx.x, j = threadIdx.x;
    if (j < 32) ld[j] = pe_f[t * 32 + j];
    __syncthreads();
    float acc = b1_f[j];
    for (int k = 0; k < 32; k++) acc = fmaf(ld[k], W1_f[(128 + k) * 128 + j], acc);
    A_timeb[t * 128 + j] = acc;
    atimb[t * 128 + j] = f2bfbits(acc);
}

__global__ void k_qws(const float* __restrict__ rela_f, const int* __restrict__ q_rel,
                      const float* __restrict__ bqr_f, const float* __restrict__ WqrT_f,
                      float* __restrict__ Q_ws) {
    alignas(16) __shared__ float qrow[4][128];
    int wv = threadIdx.x >> 6, lane = threadIdx.x & 63;
    int q = blockIdx.x * 4 + wv;
    int qr = q_rel[q];
    const float2* rp = (const float2*)(rela_f + qr * 128);
    float2 rv = rp[lane];
    qrow[wv][2 * lane] = rv.x;
    qrow[wv][2 * lane + 1] = rv.y;
    __syncthreads();
    const float4* wp = (const float4*)(WqrT_f + lane * 128);
    const float4* qp4 = (const float4*)qrow[wv];
    float acc = bqr_f[lane];
    for (int k4 = 0; k4 < 32; k4++) acc = dot4(qp4[k4], wp[k4], acc);
    Q_ws[q * 64 + lane] = acc;
}

// S_b bf16 [50000][64] = hidden[n] . Ws  (full tier only)
__global__ __launch_bounds__(256) void k_snode(const void* __restrict__ hidden,
                        const float* __restrict__ Ws_f,   // [128][64] fp32 (non-transposed)
                        const int* __restrict__ flag, unsigned short* __restrict__ S_b) {
    __shared__ float ws_lds[128][64];                 // 32 KB
    alignas(16) __shared__ float hrow[4][128];
    int tid = threadIdx.x;
    int wv = tid >> 6, lane = tid & 63;
    int f = *flag;
    for (int i = tid; i < 8192; i += 256) ((float*)ws_lds)[i] = Ws_f[i];
    __syncthreads();
    int nb = gridDim.x;
    int q0 = (int)(((long long)blockIdx.x * (N_NODE / 4)) / nb);
    int q1 = (int)(((long long)(blockIdx.x + 1) * (N_NODE / 4)) / nb);
    for (int qg = q0; qg < q1; ++qg) {
        int n = qg * 4 + wv;
        if (f) {
            ushort2 hv = ((const ushort2*)((const bf16*)hidden + (size_t)n * 128))[lane];
            hrow[wv][2 * lane]     = bfbits2f(hv.x);
            hrow[wv][2 * lane + 1] = bfbits2f(hv.y);
        } else {
            float2 hv = ((const float2*)((const float*)hidden + (size_t)n * 128))[lane];
            hrow[wv][2 * lane]     = hv.x;
            hrow[wv][2 * lane + 1] = hv.y;
        }
        float acc = 0.f;
#pragma unroll 8
        for (int k = 0; k < 128; k++) acc = fmaf(hrow[wv][k], ws_lds[k][lane], acc);
        S_b[(size_t)n * 64 + lane] = f2bfbits(acc);
    }
}

// ---------- bf16-specialized SCATTER edge kernel: runs only when *flag==1 ----------
// 32-edge groups, edge-word prefetch, S_b/Q_ws pre-gather under W2 MFMA,
// async hidden DMA, run-merged flush.
__global__ __launch_bounds__(256) void k_edge_b(
        const int* __restrict__ edges, const int* __restrict__ perm,
        const unsigned short* __restrict__ hidden,   // bf16 rows, 256B each
        const unsigned short* __restrict__ relcat,   // [r][256] A_rel|rela bf16
        const unsigned short* __restrict__ atimb,    // [t][128] bf16
        const short* __restrict__ W2pk, const short* __restrict__ Wrpk,
        const float* __restrict__ b2_f, const unsigned short* __restrict__ S_b,
        const float* __restrict__ Q_ws, const float* __restrict__ wa_f,
        const int* __restrict__ flag,
        float* __restrict__ up, float* __restrict__ bot) {
    if (*flag == 0) return;   // fp32 inputs: k_edge_s handles it
    alignas(16) __shared__ short buf[4][16][136];   // wave-private h/hr sub-tile buffer
    alignas(16) __shared__ float hid[4][32][64];    // wave-private 32 staged bf16 rows (256B)
    int wv = threadIdx.x >> 6, lane = threadIdx.x & 63;
    int c = lane & 15, q = lane >> 4;
    const int ngroups = N_EDGE / 32;  // 25000 exact

    int wvid = blockIdx.x * 4 + wv;
    int nw = gridDim.x * 4;
    int g0 = (int)(((long long)wvid * ngroups) / nw);
    int g1 = (int)(((long long)(wvid + 1) * ngroups) / nw);

    short (*bw)[136] = buf[wv];
    float (*hw)[64] = hid[wv];

    int cur_obj = -1;
    float vacc0 = 0.f, vacc1 = 0.f, eacc = 0.f;

    // prologue: edge words for first group (lanes 0..31 hold the 32 edges)
    int w0 = 0, w1 = 0, w2 = 0;
    if (g0 < g1 && lane < 32) {
        int ed = perm[g0 * 32 + lane];
        const int* ep = edges + ed * 7;
        w0 = ep[4] | (ep[0] << 16);   // sub | qi<<16
        w1 = ep[2] | (ep[6] << 16);   // rel | tim<<16
        w2 = ep[5];                   // obj
    }

    for (int g = g0; g < g1; ++g) {
        // 1) issue async DMA for all 32 hidden rows (drained per sub-tile much later)
#pragma unroll
        for (int e = 0; e < 32; e++) {
            int sub_e = __shfl(w0, e) & 0xffff;
            gld_lds4((const char*)hidden + (size_t)sub_e * 256 + lane * 4, &hw[e][0]);
        }
        // 2) prefetch next group's edge words (hides the perm->edges chain)
        int w0n = 0, w1n = 0, w2n = 0;
        if (g + 1 < g1 && lane < 32) {
            int ed = perm[(g + 1) * 32 + lane];
            const int* ep = edges + ed * 7;
            w0n = ep[4] | (ep[0] << 16);
            w1n = ep[2] | (ep[6] << 16);
            w2n = ep[5];
        }

#pragma unroll
        for (int st = 0; st < 2; st++) {
            int eb = st * 16;
            // stage h = lrelu(A_rel + A_timeb) for this 16-edge sub-tile
#pragma unroll
            for (int e2 = 0; e2 < 16; e2++) {
                int w1e = __shfl(w1, eb + e2);
                int rel_e = w1e & 0xffff, tim_e = w1e >> 16;
                ushort2 a = ((const ushort2*)(relcat + rel_e * 256))[lane];
                ushort2 t = ((const ushort2*)(atimb + tim_e * 128))[lane];
                float h0 = lrelu(bfbits2f(a.x) + bfbits2f(t.x));
                float h1 = lrelu(bfbits2f(a.y) + bfbits2f(t.y));
                *((unsigned int*)&bw[e2][2 * lane]) =
                    (unsigned)f2bfbits(h0) | ((unsigned)f2bfbits(h1) << 16);
            }

            bf16x8 hf[4];
#pragma unroll
            for (int kb = 0; kb < 4; kb++)
                hf[kb] = *((const bf16x8*)&bw[c][kb * 32 + q * 8]);

            int w04[4], w14[4];
#pragma unroll
            for (int r = 0; r < 4; r++) {
                w14[r] = __shfl(w1, eb + q * 4 + r);
                w04[r] = __shfl(w0, eb + q * 4 + r);
            }

            // pre-gather S_b (L3-resident) + Q_ws (L2): latency hides under the W2 MFMAs
            float sq[4][4];
#pragma unroll
            for (int nt = 0; nt < 4; nt++) {
                int colg = nt * 16 + c;
#pragma unroll
                for (int r = 0; r < 4; r++)
                    sq[nt][r] = bfbits2f(S_b[(w04[r] & 0xffff) * 64 + colg])
                              + Q_ws[(w04[r] >> 16) * 64 + colg];
            }

            // hr = lrelu(h@W2 + b2) + rel_e  -> buf
#pragma unroll
            for (int nt = 0; nt < 8; nt++) {
                f32x4 acc = {0.f, 0.f, 0.f, 0.f};
#pragma unroll
                for (int kb = 0; kb < 4; kb++) {
                    bf16x8 bfr = *((const bf16x8*)(W2pk + (((nt * 4 + kb) * 64) + lane) * 8));
                    acc = __builtin_amdgcn_mfma_f32_16x16x32_bf16(hf[kb], bfr, acc, 0, 0, 0);
                }
                int colg = nt * 16 + c;
                float b2v = b2_f[colg];
#pragma unroll
                for (int r = 0; r < 4; r++) {
                    float rv = bfbits2f(relcat[(w14[r] & 0xffff) * 256 + 128 + colg]);
                    bw[q * 4 + r][colg] = (short)f2bfbits(lrelu(acc[r] + b2v) + rv);
                }
            }

#pragma unroll
            for (int kb = 0; kb < 4; kb++)
                hf[kb] = *((const bf16x8*)&bw[c][kb * 32 + q * 8]);

            // att = lrelu(S_node + Q_ws + hr@Wr) . w_alpha  (S_node+Q_ws pre-gathered)
            float asum[4] = {0.f, 0.f, 0.f, 0.f};
#pragma unroll
            for (int nt = 0; nt < 4; nt++) {
                f32x4 acc = {0.f, 0.f, 0.f, 0.f};
#pragma unroll
                for (int kb = 0; kb < 4; kb++) {
                    bf16x8 bfr = *((const bf16x8*)(Wrpk + (((nt * 4 + kb) * 64) + lane) * 8));
                    acc = __builtin_amdgcn_mfma_f32_16x16x32_bf16(hf[kb], bfr, acc, 0, 0, 0);
                }
                float wav = wa_f[(nt * 16 + c) & 63];
#pragma unroll
                for (int r = 0; r < 4; r++)
                    asum[r] += lrelu(acc[r] + sq[nt][r]) * wav;
            }
            float ea[4];
#pragma unroll
            for (int r = 0; r < 4; r++) {
                float a = asum[r];
                a += __shfl_xor(a, 1); a += __shfl_xor(a, 2);
                a += __shfl_xor(a, 4); a += __shfl_xor(a, 8);
                ea[r] = __expf(a);
            }

            // drain DMA (issued at group top, long covered), scatter this sub-tile from LDS
            asm volatile("s_waitcnt vmcnt(0)" ::: "memory");
            __builtin_amdgcn_sched_barrier(0);

#pragma unroll
            for (int e2 = 0; e2 < 16; e2++) {
                float eav = __shfl(ea[e2 & 3], (e2 >> 2) * 16);
                int obj_e = __builtin_amdgcn_readfirstlane(__shfl(w2, eb + e2));
                unsigned int pk = *((const unsigned int*)&bw[e2][2 * lane]);
                float hr0 = bfbits2f((unsigned short)(pk & 0xffffu));
                float hr1 = bfbits2f((unsigned short)(pk >> 16));
                unsigned int hb = ((const unsigned int*)&hw[eb + e2][0])[lane];
                float hs0 = bfbits2f((unsigned short)(hb & 0xffffu));
                float hs1 = bfbits2f((unsigned short)(hb >> 16));
                float v0 = eav * (hs0 + hr0);
                float v1 = eav * (hs1 + hr1);
                if (obj_e != cur_obj) {
                    if (cur_obj >= 0) {
                        float* dst = up + cur_obj * 128 + 2 * lane;
                        unsafeAtomicAdd(dst,     vacc0);
                        unsafeAtomicAdd(dst + 1, vacc1);
                        if (lane == 0) unsafeAtomicAdd(bot + cur_obj, eacc);
                    }
                    cur_obj = obj_e;
                    vacc0 = v0; vacc1 = v1; eacc = eav;
                } else {
                    vacc0 += v0; vacc1 += v1; eacc += eav;
                }
            }
        }
        w0 = w0n; w1 = w1n; w2 = w2n;
    }
    if (cur_obj >= 0) {
        float* dst = up + cur_obj * 128 + 2 * lane;
        unsafeAtomicAdd(dst,     vacc0);
        unsafeAtomicAdd(dst + 1, vacc1);
        if (lane == 0) unsafeAtomicAdd(bot + cur_obj, eacc);
    }
}

// ---------- fp32 SCATTER edge kernel: runs only when *flag==0 (16-edge groups) ----------
__global__ __launch_bounds__(256) void k_edge_s(
        const int* __restrict__ edges, const int* __restrict__ perm,
        const void* __restrict__ hidden,
        const unsigned short* __restrict__ relcat,
        const unsigned short* __restrict__ atimb,
        const short* __restrict__ W2pk, const short* __restrict__ Wrpk,
        const float* __restrict__ b2_f, const unsigned short* __restrict__ S_b,
        const float* __restrict__ Q_ws, const float* __restrict__ wa_f,
        const int* __restrict__ flag,
        float* __restrict__ up, float* __restrict__ bot) {
    if (*flag == 1) return;   // bf16 inputs: k_edge_b handles it
    alignas(16) __shared__ short buf[4][16][136];
    alignas(16) __shared__ float hid[4][16][128];
    int wv = threadIdx.x >> 6, lane = threadIdx.x & 63;
    int c = lane & 15, q = lane >> 4;
    const int ngroups = N_EDGE / 16;

    int wvid = blockIdx.x * 4 + wv;
    int nw = gridDim.x * 4;
    int g0 = (int)(((long long)wvid * ngroups) / nw);
    int g1 = (int)(((long long)(wvid + 1) * ngroups) / nw);

    short (*bw)[136] = buf[wv];
    float (*hw)[128] = hid[wv];

    int cur_obj = -1;
    float vacc0 = 0.f, vacc1 = 0.f, eacc = 0.f;

    for (int g = g0; g < g1; ++g) {
        int base = g * 16;
        int w0 = 0, w1 = 0, w2 = 0;
        if (lane < 16) {
            int ed = perm[base + lane];
            const int* ep = edges + ed * 7;
            w0 = ep[4] | (ep[0] << 16);
            w1 = ep[2] | (ep[6] << 16);
            w2 = ep[5];
        }
#pragma unroll
        for (int e = 0; e < 16; e++) {
            int sub_e = __shfl(w0, e) & 0xffff;
            const char* src = (const char*)hidden + (size_t)sub_e * 512 + lane * 4;
            gld_lds4(src,       &hw[e][0]);
            gld_lds4(src + 256, &hw[e][64]);
        }
#pragma unroll
        for (int e = 0; e < 16; e++) {
            int w1e = __shfl(w1, e);
            int rel_e = w1e & 0xffff, tim_e = w1e >> 16;
            ushort2 a = ((const ushort2*)(relcat + rel_e * 256))[lane];
            ushort2 t = ((const ushort2*)(atimb + tim_e * 128))[lane];
            float h0 = lrelu(bfbits2f(a.x) + bfbits2f(t.x));
            float h1 = lrelu(bfbits2f(a.y) + bfbits2f(t.y));
            *((unsigned int*)&bw[e][2 * lane]) =
                (unsigned)f2bfbits(h0) | ((unsigned)f2bfbits(h1) << 16);
        }
        bf16x8 hf[4];
#pragma unroll
        for (int kb = 0; kb < 4; kb++)
            hf[kb] = *((const bf16x8*)&bw[c][kb * 32 + q * 8]);
        int w04[4], w14[4];
#pragma unroll
        for (int r = 0; r < 4; r++) {
            w14[r] = __shfl(w1, q * 4 + r);
            w04[r] = __shfl(w0, q * 4 + r);
        }
#pragma unroll
        for (int nt = 0; nt < 8; nt++) {
            f32x4 acc = {0.f, 0.f, 0.f, 0.f};
#pragma unroll
            for (int kb = 0; kb < 4; kb++) {
                bf16x8 bfr = *((const bf16x8*)(W2pk + (((nt * 4 + kb) * 64) + lane) * 8));
                acc = __builtin_amdgcn_mfma_f32_16x16x32_bf16(hf[kb], bfr, acc, 0, 0, 0);
            }
            int colg = nt * 16 + c;
            float b2v = b2_f[colg];
#pragma unroll
            for (int r = 0; r < 4; r++) {
                float rv = bfbits2f(relcat[(w14[r] & 0xffff) * 256 + 128 + colg]);
                bw[q * 4 + r][colg] = (short)f2bfbits(lrelu(acc[r] + b2v) + rv);
            }
        }
#pragma unroll
        for (int kb = 0; kb < 4; kb++)
            hf[kb] = *((const bf16x8*)&bw[c][kb * 32 + q * 8]);
        float asum[4] = {0.f, 0.f, 0.f, 0.f};
#pragma unroll
        for (int nt = 0; nt < 4; nt++) {
            f32x4 acc = {0.f, 0.f, 0.f, 0.f};
#pragma unroll
            for (int kb = 0; kb < 4; kb++) {
                bf16x8 bfr = *((const bf16x8*)(Wrpk + (((nt * 4 + kb) * 64) + lane) * 8));
                acc = __builtin_amdgcn_mfma_f32_16x16x32_bf16(hf[kb], bfr, acc, 0, 0, 0);
            }
            int colg = nt * 16 + c;
            float wav = wa_f[colg & 63];
#pragma unroll
            for (int r = 0; r < 4; r++) {
                float av = acc[r] + bfbits2f(S_b[(w04[r] & 0xffff) * 64 + colg])
                         + Q_ws[(w04[r] >> 16) * 64 + colg];
                asum[r] += lrelu(av) * wav;
            }
        }
        float ea[4];
#pragma unroll
        for (int r = 0; r < 4; r++) {
            float a = asum[r];
            a += __shfl_xor(a, 1); a += __shfl_xor(a, 2);
            a += __shfl_xor(a, 4); a += __shfl_xor(a, 8);
            ea[r] = __expf(a);
        }
        asm volatile("s_waitcnt vmcnt(0)" ::: "memory");
        __builtin_amdgcn_sched_barrier(0);
#pragma unroll
        for (int e = 0; e < 16; e++) {
            float eav = __shfl(ea[e & 3], (e >> 2) * 16);
            int obj_e = __builtin_amdgcn_readfirstlane(__shfl(w2, e));
            unsigned int pk = *((const unsigned int*)&bw[e][2 * lane]);
            float hr0 = bfbits2f((unsigned short)(pk & 0xffffu));
            float hr1 = bfbits2f((unsigned short)(pk >> 16));
            float2 hv = ((const float2*)&hw[e][0])[lane];
            float hs0 = hv.x, hs1 = hv.y;
            float v0 = eav * (hs0 + hr0);
            float v1 = eav * (hs1 + hr1);
            if (obj_e != cur_obj) {
                if (cur_obj >= 0) {
                    float* dst = up + cur_obj * 128 + 2 * lane;
                    unsafeAtomicAdd(dst,     vacc0);
                    unsafeAtomicAdd(dst + 1, vacc1);
                    if (lane == 0) unsafeAtomicAdd(bot + cur_obj, eacc);
                }
                cur_obj = obj_e;
                vacc0 = v0; vacc1 = v1; eacc = eav;
            } else {
                vacc0 += v0; vacc1 += v1; eacc += eav;
            }
        }
    }
    if (cur_obj >= 0) {
        float* dst = up + cur_obj * 128 + 2 * lane;
        unsafeAtomicAdd(dst,     vacc0);
        unsafeAtomicAdd(dst + 1, vacc1);
        if (lane == 0) unsafeAtomicAdd(bot + cur_obj, eacc);
    }
}

// ---------- COMPACT-tier fallback (atomics into d_out) ----------
__global__ __launch_bounds__(256) void k_edge_c(
        const int* __restrict__ edges, const void* __restrict__ hidden,
        const float* __restrict__ rela_f,
        const float* __restrict__ A_rel, const float* __restrict__ A_timeb,
        const float* __restrict__ W2T, const float* __restrict__ WrT,
        const float* __restrict__ WsT, const float* __restrict__ b2_f,
        const float* __restrict__ Q_ws, const float* __restrict__ wa_f,
        const int* __restrict__ flag,
        float* __restrict__ bot, void* __restrict__ dout) {
    alignas(16) __shared__ float lds_h[4][EPW][128];
    alignas(16) __shared__ float lds_hr[4][EPW][128];
    alignas(16) __shared__ float lds_hs[4][EPW][128];
    int wv = threadIdx.x >> 6, lane = threadIdx.x & 63;
    int f = *flag;
    int nwaves = gridDim.x * 4;
    const int ngroups = N_EDGE / EPW;
    float b20 = b2_f[2 * lane], b21 = b2_f[2 * lane + 1];
    float wa = wa_f[lane];
    for (int g = blockIdx.x * 4 + wv; g < ngroups; g += nwaves) {
        int base = g * EPW;
        int rel[EPW], sub[EPW], obj[EPW], qi[EPW], tim[EPW];
#pragma unroll
        for (int e = 0; e < EPW; e++) {
            const int* ep = edges + (base + e) * 7;
            qi[e] = ep[0]; rel[e] = ep[2]; sub[e] = ep[4];
            obj[e] = ep[5]; tim[e] = ep[6];
        }
        float hs0[EPW], hs1[EPW];
#pragma unroll
        for (int e = 0; e < EPW; e++) {
            const float2* ar = (const float2*)(A_rel + rel[e] * 128);
            const float2* at = (const float2*)(A_timeb + tim[e] * 128);
            float2 a = ar[lane], t = at[lane];
            lds_h[wv][e][2 * lane]     = lrelu(a.x + t.x);
            lds_h[wv][e][2 * lane + 1] = lrelu(a.y + t.y);
            if (f) {
                ushort2 hv = ((const ushort2*)((const bf16*)hidden + sub[e] * 128))[lane];
                hs0[e] = bfbits2f(hv.x); hs1[e] = bfbits2f(hv.y);
            } else {
                float2 hv = ((const float2*)((const float*)hidden + sub[e] * 128))[lane];
                hs0[e] = hv.x; hs1[e] = hv.y;
            }
            lds_hs[wv][e][2 * lane]     = hs0[e];
            lds_hs[wv][e][2 * lane + 1] = hs1[e];
        }
        float acc0[EPW], acc1[EPW];
#pragma unroll
        for (int e = 0; e < EPW; e++) { acc0[e] = b20; acc1[e] = b21; }
        const float4* w0p = (const float4*)(W2T + (2 * lane) * 128);
        const float4* w1p = (const float4*)(W2T + (2 * lane + 1) * 128);
        for (int k4 = 0; k4 < 32; k4++) {
            float4 w0 = w0p[k4], w1 = w1p[k4];
#pragma unroll
            for (int e = 0; e < EPW; e++) {
                float4 h = ((const float4*)lds_h[wv][e])[k4];
                acc0[e] = dot4(h, w0, acc0[e]);
                acc1[e] = dot4(h, w1, acc1[e]);
            }
        }
        float hr0[EPW], hr1[EPW];
#pragma unroll
        for (int e = 0; e < EPW; e++) {
            const float2* rp = (const float2*)(rela_f + rel[e] * 128);
            float2 rv = rp[lane];
            hr0[e] = lrelu(acc0[e]) + rv.x;
            hr1[e] = lrelu(acc1[e]) + rv.y;
            lds_hr[wv][e][2 * lane]     = hr0[e];
            lds_hr[wv][e][2 * lane + 1] = hr1[e];
        }
        float att[EPW];
#pragma unroll
        for (int e = 0; e < EPW; e++) att[e] = Q_ws[qi[e] * 64 + lane];
        const float4* wrp = (const float4*)(WrT + lane * 128);
        const float4* wsp = (const float4*)(WsT + lane * 128);
        for (int k4 = 0; k4 < 32; k4++) {
            float4 w = wrp[k4], w2 = wsp[k4];
#pragma unroll
            for (int e = 0; e < EPW; e++) {
                float4 hr4 = ((const float4*)lds_hr[wv][e])[k4];
                float4 hs4 = ((const float4*)lds_hs[wv][e])[k4];
                att[e] = dot4(hr4, w, att[e]);
                att[e] = dot4(hs4, w2, att[e]);
            }
        }
        float ea[EPW];
#pragma unroll
        for (int e = 0; e < EPW; e++) {
            float a = lrelu(att[e]) * wa;
            a += __shfl_xor(a, 32); a += __shfl_xor(a, 16); a += __shfl_xor(a, 8);
            a += __shfl_xor(a, 4);  a += __shfl_xor(a, 2);  a += __shfl_xor(a, 1);
            ea[e] = __expf(a);
        }
#pragma unroll
        for (int e = 0; e < EPW; e++) {
            float v0 = ea[e] * (hs0[e] + hr0[e]);
            float v1 = ea[e] * (hs1[e] + hr1[e]);
            if (!f) {
                float* dst = (float*)dout + obj[e] * 128 + 2 * lane;
                unsafeAtomicAdd(dst,     v0);
                unsafeAtomicAdd(dst + 1, v1);
            } else {
                atom_pk_bf16((unsigned int*)dout + obj[e] * 64 + lane, v0, v1);
            }
            if (lane == 0) unsafeAtomicAdd(bot + obj[e], ea[e]);
        }
    }
}

// ---------- epilogue: out[n] = (up[n]/bot[n]) @ Wh; Wh cached in LDS, block loops nodes ----------
__global__ __launch_bounds__(256) void k_out(const float* __restrict__ up,
                      const float* __restrict__ bot,
                      const float* __restrict__ Wh_f, void* __restrict__ dout,
                      const int* __restrict__ flag, int tier_full) {
    __shared__ float wh[124][128];   // 63.5 KB: rows 0..123 cached; 124..127 from L2
    __shared__ float m[2][128];
    int tid = threadIdx.x;
    int half = tid >> 7, j = tid & 127;
    int f = *flag;
    for (int i = tid; i < 124 * 128; i += 256) ((float*)wh)[i] = Wh_f[i];
    __syncthreads();
    int nb = gridDim.x;
    int p0 = (int)(((long long)blockIdx.x * (N_NODE / 2)) / nb);
    int p1 = (int)(((long long)(blockIdx.x + 1) * (N_NODE / 2)) / nb);
    for (int p = p0; p < p1; ++p) {
        int n = p * 2 + half;
        float inv = 1.f / (bot[n] + 1e-5f);
        float num;
        if (tier_full) {
            num = up[(size_t)n * 128 + j];
        } else if (!f) {
            num = ((const float*)dout)[(size_t)n * 128 + j];
        } else {
            unsigned int w = ((const unsigned int*)dout)[(size_t)n * 64 + (j >> 1)];
            num = bfbits2f((unsigned short)((j & 1) ? (w >> 16) : (w & 0xffffu)));
        }
        m[half][j] = num * inv;
        __syncthreads();
        float acc = 0.f;
#pragma unroll 4
        for (int k = 0; k < 124; k++) acc = fmaf(m[half][k], wh[k][j], acc);
#pragma unroll
        for (int k = 124; k < 128; k++) acc = fmaf(m[half][k], Wh_f[k * 128 + j], acc);
        if (f) ((bf16*)dout)[(size_t)n * 128 + j] = __float2bfloat16(acc);
        else   ((float*)dout)[(size_t)n * 128 + j] = acc;
        __syncthreads();
    }
}

// ---------- launcher ----------
extern "C" void kernel_launch(void* const* d_in, const int* in_sizes, int n_in,
                              void* d_out, int out_size, void* d_ws, size_t ws_size,
                              hipStream_t stream) {
    const void* hidden = d_in[0];
    const void* rela   = d_in[1];
    const void* pe     = d_in[2];
    const void* W1     = d_in[3];
    const void* b1     = d_in[4];
    const void* W2     = d_in[5];
    const void* b2     = d_in[6];
    const void* Ws     = d_in[7];
    const void* Wr     = d_in[8];
    const void* Wqr    = d_in[9];
    const void* bqr    = d_in[10];
    const void* walpha = d_in[11];
    const void* Wh     = d_in[12];
    const int* q_rel   = (const int*)d_in[13];
    const int* edges   = (const int*)d_in[14];

    float* ws = (float*)d_ws;
    size_t off = 0;
    int*   flag    = (int*)(ws + off); off += 4;
    float* pool    = ws + off;
    float* rela_f  = pool;
    float* pe_f    = rela_f + SEG_RELA;
    float* W1_f    = pe_f + SEG_PE;
    float* b1_f    = W1_f + SEG_W1;
    float* W2T_f   = b1_f + SEG_B1;
    float* b2_f    = W2T_f + SEG_W2T;
    float* WsT_f   = b2_f + SEG_B2;
    float* Ws_f    = WsT_f + SEG_WST;
    float* WrT_f   = Ws_f + SEG_WS;
    float* WqrT_f  = WrT_f + SEG_WRT;
    float* bqr_f   = WqrT_f + SEG_WQRT;
    float* wa_f    = bqr_f + SEG_BQR;
    float* Wh_f    = wa_f + SEG_WA;
    off += POOL_TOTAL;
    float* A_rel   = ws + off; off += 401 * 128;
    float* A_timeb = ws + off; off += 1000 * 128;
    float* Q_ws    = ws + off; off += N_QUERY * 64;
    float* bot     = ws + off; off += N_NODE;
    short* W2pk    = (short*)(ws + off); off += 8192;
    short* Wrpk    = (short*)(ws + off); off += 4096;
    unsigned short* relcat = (unsigned short*)(ws + off); off += 401 * 128;   // 401*256 bf16
    unsigned short* atimb  = (unsigned short*)(ws + off); off += 1000 * 64;   // 1000*128 bf16
    unsigned short* S_b    = (unsigned short*)(ws + off); off += (size_t)N_NODE * 32; // 50000*64 bf16
    float* up      = ws + off; off += (size_t)N_NODE * 128;
    int*   perm    = (int*)(ws + off); off += N_EDGE;
    int*   cnt     = (int*)(ws + off); off += N_NODE + 32;
    int*   cur     = (int*)(ws + off); off += N_NODE + 32;
    size_t full_floats = off;   // ~9.46M floats = 37.85 MB (proven ws >= 39.6 MB)

    int tier_full = (ws_size >= full_floats * sizeof(float)) ? 1 : 0;

    k_detect<<<1, 1, 0, stream>>>((const unsigned int*)pe, flag);
    k_zero<<<2048, 256, 0, stream>>>((unsigned int*)d_out, out_size, flag, bot, up, cnt, tier_full);
    k_convert<<<(POOL_TOTAL + 255) / 256, 256, 0, stream>>>(
        rela, pe, W1, b1, W2, b2, Ws, Wr, Wqr, bqr, walpha, Wh, flag, pool);
    k_arel<<<401, 128, 0, stream>>>(rela_f, W1_f, A_rel, relcat);
    k_atime<<<1000, 128, 0, stream>>>(pe_f, W1_f, b1_f, A_timeb, atimb);
    k_qws<<<N_QUERY / 4, 256, 0, stream>>>(rela_f, q_rel, bqr_f, WqrT_f, Q_ws);

    if (tier_full) {
        k_pack<<<96, 256, 0, stream>>>(W2T_f, WrT_f, W2pk, Wrpk);
        k_snode<<<1024, 256, 0, stream>>>(hidden, Ws_f, flag, S_b);
        k_hist<<<1024, 256, 0, stream>>>(edges, cnt);
        k_scan<<<1, SCAN_T, 0, stream>>>(cnt, cur);
        k_scat<<<1024, 256, 0, stream>>>(edges, cur, perm);
        // Device-side dtype dispatch: both launched; each early-exits on the wrong dtype.
        // 512 blocks = 2 blocks/CU (VGPR-limited) fully resident.
        k_edge_b<<<512, 256, 0, stream>>>(edges, perm, (const unsigned short*)hidden,
                                          relcat, atimb, W2pk, Wrpk, b2_f, S_b,
                                          Q_ws, wa_f, flag, up, bot);
        k_edge_s<<<512, 256, 0, stream>>>(edges, perm, hidden, relcat, atimb, W2pk, Wrpk,
                                          b2_f, S_b, Q_ws, wa_f, flag, up, bot);
    } else {
        k_edge_c<<<1536, 256, 0, stream>>>(edges, hidden, rela_f, A_rel, A_timeb,
                                           W2T_f, WrT_f, WsT_f, b2_f, Q_ws, wa_f,
                                           flag, bot, d_out);
    }

    k_out<<<500, 256, 0, stream>>>(up, bot, Wh_f, d_out, flag, tier_full);
}

// Round 11
// 1056.486 us; speedup vs baseline: 1.0690x; 1.0690x over previous
//
#include <hip/hip_runtime.h>
#include <hip/hip_bf16.h>

typedef __hip_bfloat16 bf16;
typedef __attribute__((ext_vector_type(8))) short bf16x8;
typedef __attribute__((ext_vector_type(4))) float f32x4;

#define N_NODE   50000
#define N_EDGE   800000
#define N_QUERY  512
#define EPW      8

__device__ __forceinline__ float bfbits2f(unsigned short u) {
    return __uint_as_float(((unsigned)u) << 16);
}
__device__ __forceinline__ unsigned short f2bfbits(float f) {
    unsigned int u = __float_as_uint(f);
    return (unsigned short)((u + 0x7fffu + ((u >> 16) & 1u)) >> 16);  // RNE
}
__device__ __forceinline__ float lrelu(float x) { return x > 0.f ? x : 0.01f * x; }
__device__ __forceinline__ float dot4(float4 a, float4 b, float acc) {
    acc = fmaf(a.x, b.x, acc); acc = fmaf(a.y, b.y, acc);
    acc = fmaf(a.z, b.z, acc); acc = fmaf(a.w, b.w, acc);
    return acc;
}
// async global->LDS DMA: per-lane 4B from per-lane global addr into (base + lane*4)
__device__ __forceinline__ void gld_lds4(const void* g, void* l) {
    __builtin_amdgcn_global_load_lds(
        (const __attribute__((address_space(1))) void*)g,
        (__attribute__((address_space(3))) void*)l, 4, 0, 0);
}
__device__ __forceinline__ void atom_pk_bf16(unsigned int* addr, float a0, float a1) {
    unsigned int old = *((volatile unsigned int*)addr);
    while (true) {
        float f0 = bfbits2f((unsigned short)(old & 0xffffu)) + a0;
        float f1 = bfbits2f((unsigned short)(old >> 16)) + a1;
        unsigned int nv = (unsigned int)f2bfbits(f0) | ((unsigned int)f2bfbits(f1) << 16);
        unsigned int prev = atomicCAS(addr, old, nv);
        if (prev == old) break;
        old = prev;
    }
}

// ---------- dtype detection (pe[0] word: fp32 -> 0x00000000, bf16 -> 0x3F800000) ----------
__global__ void k_detect(const unsigned int* __restrict__ pe_raw, int* __restrict__ flag) {
    *flag = (pe_raw[0] != 0u) ? 1 : 0;   // 1 = bf16 inputs, 0 = fp32 inputs (measured: 0)
}

// ---------- zero accumulators (+ sort histogram) ----------
__global__ void k_zero(unsigned int* __restrict__ out_w, int out_elems,
                       const int* __restrict__ flag,
                       float* __restrict__ bot, float* __restrict__ up,
                       int* __restrict__ cnt, int tier_full) {
    int f = *flag;
    int stride = gridDim.x * blockDim.x;
    int tid = blockIdx.x * blockDim.x + threadIdx.x;
    for (int i = tid; i < N_NODE; i += stride) bot[i] = 0.f;
    if (tier_full) {
        for (int i = tid; i < N_NODE * 128; i += stride) up[i] = 0.f;
        for (int i = tid; i < N_NODE + 32; i += stride) cnt[i] = 0;
    } else {
        int out_words = f ? (out_elems >> 1) : out_elems;
        for (int i = tid; i < out_words; i += stride) out_w[i] = 0u;
    }
}

// ---------- counting sort of edges by obj: hist -> scan -> scatter ----------
__global__ void k_hist(const int* __restrict__ edges, int* __restrict__ cnt) {
    int stride = gridDim.x * blockDim.x;
    for (int i = blockIdx.x * blockDim.x + threadIdx.x; i < N_EDGE; i += stride)
        atomicAdd(&cnt[edges[i * 7 + 5]], 1);
}

#define SCAN_T 1024
#define SCAN_C 49   // 1024*49 = 50176 >= N_NODE
__global__ void k_scan(const int* __restrict__ cnt, int* __restrict__ cur) {
    __shared__ int part[SCAN_T];
    int t = threadIdx.x;
    int beg = t * SCAN_C;
    int s = 0;
    for (int i = 0; i < SCAN_C; i++) {
        int idx = beg + i;
        if (idx < N_NODE) s += cnt[idx];
    }
    part[t] = s;
    __syncthreads();
    for (int d = 1; d < SCAN_T; d <<= 1) {
        int v = (t >= d) ? part[t - d] : 0;
        __syncthreads();
        part[t] += v;
        __syncthreads();
    }
    int run = (t == 0) ? 0 : part[t - 1];
    for (int i = 0; i < SCAN_C; i++) {
        int idx = beg + i;
        if (idx < N_NODE) { cur[idx] = run; run += cnt[idx]; }
    }
}

__global__ void k_scat(const int* __restrict__ edges, int* __restrict__ cur,
                       int* __restrict__ perm) {
    int stride = gridDim.x * blockDim.x;
    for (int i = blockIdx.x * blockDim.x + threadIdx.x; i < N_EDGE; i += stride) {
        int obj = edges[i * 7 + 5];
        int pos = atomicAdd(&cur[obj], 1);
        perm[pos] = i;
    }
}

// ---------- convert all small tensors to fp32 pool (transposes W2/Ws/Wr/Wqr) ----------
#define SEG_RELA   51328
#define SEG_PE     32000
#define SEG_W1     20480
#define SEG_B1     128
#define SEG_W2T    16384
#define SEG_B2     128
#define SEG_WST    8192
#define SEG_WS     8192
#define SEG_WRT    8192
#define SEG_WQRT   8192
#define SEG_BQR    64
#define SEG_WA     64
#define SEG_WH     16384
#define POOL_TOTAL (SEG_RELA+SEG_PE+SEG_W1+SEG_B1+SEG_W2T+SEG_B2+SEG_WST+SEG_WS+SEG_WRT+SEG_WQRT+SEG_BQR+SEG_WA+SEG_WH)

__global__ void k_convert(const void* rela, const void* pe, const void* W1, const void* b1,
                          const void* W2, const void* b2, const void* Ws, const void* Wr,
                          const void* Wqr, const void* bqr, const void* walpha, const void* Wh,
                          const int* __restrict__ flag, float* __restrict__ pool) {
    int idx = blockIdx.x * blockDim.x + threadIdx.x;
    int f = *flag;
    auto ld = [&](const void* p, int i) -> float {
        return f ? __bfloat162float(((const bf16*)p)[i]) : ((const float*)p)[i];
    };
    int i = idx;
    if (i < SEG_RELA) { pool[idx] = ld(rela, i); return; } i -= SEG_RELA;
    if (i < SEG_PE)   { pool[idx] = ld(pe, i); return; }   i -= SEG_PE;
    if (i < SEG_W1)   { pool[idx] = ld(W1, i); return; }   i -= SEG_W1;
    if (i < SEG_B1)   { pool[idx] = ld(b1, i); return; }   i -= SEG_B1;
    if (i < SEG_W2T)  { pool[idx] = ld(W2, (i & 127) * 128 + (i >> 7)); return; } i -= SEG_W2T;
    if (i < SEG_B2)   { pool[idx] = ld(b2, i); return; }   i -= SEG_B2;
    if (i < SEG_WST)  { pool[idx] = ld(Ws,  (i & 127) * 64 + (i >> 7)); return; } i -= SEG_WST;
    if (i < SEG_WS)   { pool[idx] = ld(Ws, i); return; }   i -= SEG_WS;
    if (i < SEG_WRT)  { pool[idx] = ld(Wr,  (i & 127) * 64 + (i >> 7)); return; } i -= SEG_WRT;
    if (i < SEG_WQRT) { pool[idx] = ld(Wqr, (i & 127) * 64 + (i >> 7)); return; } i -= SEG_WQRT;
    if (i < SEG_BQR)  { pool[idx] = ld(bqr, i); return; }  i -= SEG_BQR;
    if (i < SEG_WA)   { pool[idx] = ld(walpha, i); return; } i -= SEG_WA;
    if (i < SEG_WH)   { pool[idx] = ld(Wh, i); return; }
}

// ---------- pack W2/Wr into MFMA B-fragment order (bf16) ----------
__global__ void k_pack(const float* __restrict__ W2T_f, const float* __restrict__ WrT_f,
                       short* __restrict__ W2pk, short* __restrict__ Wrpk) {
    int idx = blockIdx.x * blockDim.x + threadIdx.x;
    if (idx < 16384) {
        int j = idx & 7, lane = (idx >> 3) & 63, kb = (idx >> 9) & 3, nt = idx >> 11;
        int k = kb * 32 + (lane >> 4) * 8 + j, n = nt * 16 + (lane & 15);
        W2pk[idx] = (short)f2bfbits(W2T_f[n * 128 + k]);
    } else if (idx < 16384 + 8192) {
        int i2 = idx - 16384;
        int j = i2 & 7, lane = (i2 >> 3) & 63, kb = (i2 >> 9) & 3, nt = i2 >> 11;
        int k = kb * 32 + (lane >> 4) * 8 + j, n = nt * 16 + (lane & 15);
        Wrpk[i2] = (short)f2bfbits(WrT_f[n * 128 + k]);
    }
}

// ---------- precompute tables ----------
__global__ void k_arel(const float* __restrict__ rela_f, const float* __restrict__ W1_f,
                       float* __restrict__ A_rel, unsigned short* __restrict__ relcat) {
    __shared__ float ld[128];
    int r = blockIdx.x, j = threadIdx.x;
    float rv = rela_f[r * 128 + j];
    ld[j] = rv;
    __syncthreads();
    float acc = 0.f;
    for (int k = 0; k < 128; k++) acc = fmaf(ld[k], W1_f[k * 128 + j], acc);
    A_rel[r * 128 + j] = acc;
    relcat[r * 256 + j] = f2bfbits(acc);
    relcat[r * 256 + 128 + j] = f2bfbits(rv);
}

__global__ void k_atime(const float* __restrict__ pe_f, const float* __restrict__ W1_f,
                        const float* __restrict__ b1_f, float* __restrict__ A_timeb,
                        unsigned short* __restrict__ atimb) {
    __shared__ float ld[32];
    int t = blockIdx.x, j = threadIdx.x;
    if (j < 32) ld[j] = pe_f[t * 32 + j];
    __syncthreads();
    float acc = b1_f[j];
    for (int k = 0; k < 32; k++) acc = fmaf(ld[k], W1_f[(128 + k) * 128 + j], acc);
    A_timeb[t * 128 + j] = acc;
    atimb[t * 128 + j] = f2bfbits(acc);
}

__global__ void k_qws(const float* __restrict__ rela_f, const int* __restrict__ q_rel,
                      const float* __restrict__ bqr_f, const float* __restrict__ WqrT_f,
                      float* __restrict__ Q_ws) {
    alignas(16) __shared__ float qrow[4][128];
    int wv = threadIdx.x >> 6, lane = threadIdx.x & 63;
    int q = blockIdx.x * 4 + wv;
    int qr = q_rel[q];
    const float2* rp = (const float2*)(rela_f + qr * 128);
    float2 rv = rp[lane];
    qrow[wv][2 * lane] = rv.x;
    qrow[wv][2 * lane + 1] = rv.y;
    __syncthreads();
    const float4* wp = (const float4*)(WqrT_f + lane * 128);
    const float4* qp4 = (const float4*)qrow[wv];
    float acc = bqr_f[lane];
    for (int k4 = 0; k4 < 32; k4++) acc = dot4(qp4[k4], wp[k4], acc);
    Q_ws[q * 64 + lane] = acc;
}

// S_b bf16 [50000][64] = hidden[n] . Ws  (full tier only)
__global__ __launch_bounds__(256) void k_snode(const void* __restrict__ hidden,
                        const float* __restrict__ Ws_f,   // [128][64] fp32 (non-transposed)
                        const int* __restrict__ flag, unsigned short* __restrict__ S_b) {
    __shared__ float ws_lds[128][64];                 // 32 KB
    alignas(16) __shared__ float hrow[4][128];
    int tid = threadIdx.x;
    int wv = tid >> 6, lane = tid & 63;
    int f = *flag;
    for (int i = tid; i < 8192; i += 256) ((float*)ws_lds)[i] = Ws_f[i];
    __syncthreads();
    int nb = gridDim.x;
    int q0 = (int)(((long long)blockIdx.x * (N_NODE / 4)) / nb);
    int q1 = (int)(((long long)(blockIdx.x + 1) * (N_NODE / 4)) / nb);
    for (int qg = q0; qg < q1; ++qg) {
        int n = qg * 4 + wv;
        if (f) {
            ushort2 hv = ((const ushort2*)((const bf16*)hidden + (size_t)n * 128))[lane];
            hrow[wv][2 * lane]     = bfbits2f(hv.x);
            hrow[wv][2 * lane + 1] = bfbits2f(hv.y);
        } else {
            float2 hv = ((const float2*)((const float*)hidden + (size_t)n * 128))[lane];
            hrow[wv][2 * lane]     = hv.x;
            hrow[wv][2 * lane + 1] = hv.y;
        }
        float acc = 0.f;
#pragma unroll 8
        for (int k = 0; k < 128; k++) acc = fmaf(hrow[wv][k], ws_lds[k][lane], acc);
        S_b[(size_t)n * 64 + lane] = f2bfbits(acc);
    }
}

// ---------- SCATTER edge kernel: R8 body + next-group prefetch + S_b/Q_ws pre-gather ----------
// Single generic kernel (R10 lesson: specialization/co-compilation perturbs codegen badly).
__global__ __launch_bounds__(256) void k_edge_s(
        const int* __restrict__ edges, const int* __restrict__ perm,
        const void* __restrict__ hidden,
        const unsigned short* __restrict__ relcat,   // [r][256] A_rel|rela bf16
        const unsigned short* __restrict__ atimb,    // [t][128] bf16
        const short* __restrict__ W2pk, const short* __restrict__ Wrpk,
        const float* __restrict__ b2_f, const unsigned short* __restrict__ S_b,
        const float* __restrict__ Q_ws, const float* __restrict__ wa_f,
        const int* __restrict__ flag,
        float* __restrict__ up, float* __restrict__ bot) {
    alignas(16) __shared__ short buf[4][16][136];   // wave-private h -> hr buffer
    alignas(16) __shared__ float hid[4][16][128];   // wave-private staged hidden rows (raw)
    int wv = threadIdx.x >> 6, lane = threadIdx.x & 63;
    int c = lane & 15, q = lane >> 4;
    int f = *flag;
    const int ngroups = N_EDGE / 16;  // 50000 exact

    // contiguous span of sorted groups per wave -> runs merge across groups
    int wvid = blockIdx.x * 4 + wv;
    int nw = gridDim.x * 4;
    int g0 = (int)(((long long)wvid * ngroups) / nw);
    int g1 = (int)(((long long)(wvid + 1) * ngroups) / nw);

    short (*bw)[136] = buf[wv];
    float (*hw)[128] = hid[wv];

    int cur_obj = -1;
    float vacc0 = 0.f, vacc1 = 0.f, eacc = 0.f;

    // prologue: first group's edge words
    int w0 = 0, w1 = 0, w2 = 0;
    if (g0 < g1 && lane < 16) {
        int ed = perm[g0 * 16 + lane];
        const int* ep = edges + ed * 7;
        w0 = ep[4] | (ep[0] << 16);   // sub | qi<<16   (both < 65536)
        w1 = ep[2] | (ep[6] << 16);   // rel | tim<<16
        w2 = ep[5];                   // obj
    }

    for (int g = g0; g < g1; ++g) {
        // issue async hidden-row DMA for all 16 edges; consumed in the scatter phase.
        if (f) {
#pragma unroll
            for (int e = 0; e < 16; e++) {
                int sub_e = __shfl(w0, e) & 0xffff;
                const char* src = (const char*)hidden + (size_t)sub_e * 256 + lane * 4;
                gld_lds4(src, &hw[e][0]);               // 256B row (bf16)
            }
        } else {
#pragma unroll
            for (int e = 0; e < 16; e++) {
                int sub_e = __shfl(w0, e) & 0xffff;
                const char* src = (const char*)hidden + (size_t)sub_e * 512 + lane * 4;
                gld_lds4(src,       &hw[e][0]);         // floats 0..63
                gld_lds4(src + 256, &hw[e][64]);        // floats 64..127
            }
        }

        // prefetch NEXT group's edge words: hides the perm->edges dependent chain
        int w0n = 0, w1n = 0, w2n = 0;
        if (g + 1 < g1 && lane < 16) {
            int ed = perm[(g + 1) * 16 + lane];
            const int* ep = edges + ed * 7;
            w0n = ep[4] | (ep[0] << 16);
            w1n = ep[2] | (ep[6] << 16);
            w2n = ep[5];
        }

        // stage h = lrelu(A_rel + A_timeb) (bf16 coalesced reads) into LDS
#pragma unroll
        for (int e = 0; e < 16; e++) {
            int w1e = __shfl(w1, e);
            int rel_e = w1e & 0xffff, tim_e = w1e >> 16;
            ushort2 a = ((const ushort2*)(relcat + rel_e * 256))[lane];
            ushort2 t = ((const ushort2*)(atimb + tim_e * 128))[lane];
            float h0 = lrelu(bfbits2f(a.x) + bfbits2f(t.x));
            float h1 = lrelu(bfbits2f(a.y) + bfbits2f(t.y));
            *((unsigned int*)&bw[e][2 * lane]) =
                (unsigned)f2bfbits(h0) | ((unsigned)f2bfbits(h1) << 16);
        }

        bf16x8 hf[4];
#pragma unroll
        for (int kb = 0; kb < 4; kb++)
            hf[kb] = *((const bf16x8*)&bw[c][kb * 32 + q * 8]);

        // per-lane row metadata packed (rel=w14&0xffff, sub=w04&0xffff, qi=w04>>16)
        int w04[4], w14[4];
#pragma unroll
        for (int r = 0; r < 4; r++) {
            w14[r] = __shfl(w1, q * 4 + r);
            w04[r] = __shfl(w0, q * 4 + r);
        }

        // pre-gather S_b (L3, ~900cy) + Q_ws (L2): latency hides under the W2 MFMA phase
        float sq[4][4];
#pragma unroll
        for (int nt = 0; nt < 4; nt++) {
            int colg = nt * 16 + c;
#pragma unroll
            for (int r = 0; r < 4; r++)
                sq[nt][r] = bfbits2f(S_b[(w04[r] & 0xffff) * 64 + colg])
                          + Q_ws[(w04[r] >> 16) * 64 + colg];
        }

        // hr = lrelu(h@W2 + b2) + rel_e  -> buf (fixup folded into epilogue)
#pragma unroll
        for (int nt = 0; nt < 8; nt++) {
            f32x4 acc = {0.f, 0.f, 0.f, 0.f};
#pragma unroll
            for (int kb = 0; kb < 4; kb++) {
                bf16x8 bfr = *((const bf16x8*)(W2pk + (((nt * 4 + kb) * 64) + lane) * 8));
                acc = __builtin_amdgcn_mfma_f32_16x16x32_bf16(hf[kb], bfr, acc, 0, 0, 0);
            }
            int colg = nt * 16 + c;
            float b2v = b2_f[colg];
#pragma unroll
            for (int r = 0; r < 4; r++) {
                float rv = bfbits2f(relcat[(w14[r] & 0xffff) * 256 + 128 + colg]);
                bw[q * 4 + r][colg] = (short)f2bfbits(lrelu(acc[r] + b2v) + rv);
            }
        }

        // reload fragments (now hr) into the same registers
#pragma unroll
        for (int kb = 0; kb < 4; kb++)
            hf[kb] = *((const bf16x8*)&bw[c][kb * 32 + q * 8]);

        // att = lrelu(S_node + Q_ws + hr@Wr) . w_alpha  (S_node+Q_ws pre-gathered)
        float asum[4] = {0.f, 0.f, 0.f, 0.f};
#pragma unroll
        for (int nt = 0; nt < 4; nt++) {
            f32x4 acc = {0.f, 0.f, 0.f, 0.f};
#pragma unroll
            for (int kb = 0; kb < 4; kb++) {
                bf16x8 bfr = *((const bf16x8*)(Wrpk + (((nt * 4 + kb) * 64) + lane) * 8));
                acc = __builtin_amdgcn_mfma_f32_16x16x32_bf16(hf[kb], bfr, acc, 0, 0, 0);
            }
            int colg = nt * 16 + c;
            float wav = wa_f[colg & 63];
#pragma unroll
            for (int r = 0; r < 4; r++)
                asum[r] += lrelu(acc[r] + sq[nt][r]) * wav;
        }
        float ea[4];
#pragma unroll
        for (int r = 0; r < 4; r++) {
            float a = asum[r];
            a += __shfl_xor(a, 1); a += __shfl_xor(a, 2);
            a += __shfl_xor(a, 4); a += __shfl_xor(a, 8);
            ea[r] = __expf(a);
        }

        // drain the hidden DMA (long since issued), then scatter purely from LDS
        asm volatile("s_waitcnt vmcnt(0)" ::: "memory");
        __builtin_amdgcn_sched_barrier(0);

        // run-merged scatter: edges arrive obj-sorted; flush once per run
#pragma unroll
        for (int e = 0; e < 16; e++) {
            float eav = __shfl(ea[e & 3], (e >> 2) * 16);
            int obj_e = __builtin_amdgcn_readfirstlane(__shfl(w2, e));
            unsigned int pk = *((const unsigned int*)&bw[e][2 * lane]);
            float hr0 = bfbits2f((unsigned short)(pk & 0xffffu));
            float hr1 = bfbits2f((unsigned short)(pk >> 16));
            float hs0, hs1;
            if (f) {
                unsigned int hb = ((const unsigned int*)&hw[e][0])[lane];
                hs0 = bfbits2f((unsigned short)(hb & 0xffffu));
                hs1 = bfbits2f((unsigned short)(hb >> 16));
            } else {
                float2 hv = ((const float2*)&hw[e][0])[lane];
                hs0 = hv.x; hs1 = hv.y;
            }
            float v0 = eav * (hs0 + hr0);
            float v1 = eav * (hs1 + hr1);
            if (obj_e != cur_obj) {
                if (cur_obj >= 0) {
                    float* dst = up + cur_obj * 128 + 2 * lane;
                    unsafeAtomicAdd(dst,     vacc0);
                    unsafeAtomicAdd(dst + 1, vacc1);
                    if (lane == 0) unsafeAtomicAdd(bot + cur_obj, eacc);
                }
                cur_obj = obj_e;
                vacc0 = v0; vacc1 = v1; eacc = eav;
            } else {
                vacc0 += v0; vacc1 += v1; eacc += eav;
            }
        }

        w0 = w0n; w1 = w1n; w2 = w2n;
    }
    // final flush of the span's trailing run
    if (cur_obj >= 0) {
        float* dst = up + cur_obj * 128 + 2 * lane;
        unsafeAtomicAdd(dst,     vacc0);
        unsafeAtomicAdd(dst + 1, vacc1);
        if (lane == 0) unsafeAtomicAdd(bot + cur_obj, eacc);
    }
}

// ---------- COMPACT-tier fallback (atomics into d_out) ----------
__global__ __launch_bounds__(256) void k_edge_c(
        const int* __restrict__ edges, const void* __restrict__ hidden,
        const float* __restrict__ rela_f,
        const float* __restrict__ A_rel, const float* __restrict__ A_timeb,
        const float* __restrict__ W2T, const float* __restrict__ WrT,
        const float* __restrict__ WsT, const float* __restrict__ b2_f,
        const float* __restrict__ Q_ws, const float* __restrict__ wa_f,
        const int* __restrict__ flag,
        float* __restrict__ bot, void* __restrict__ dout) {
    alignas(16) __shared__ float lds_h[4][EPW][128];
    alignas(16) __shared__ float lds_hr[4][EPW][128];
    alignas(16) __shared__ float lds_hs[4][EPW][128];
    int wv = threadIdx.x >> 6, lane = threadIdx.x & 63;
    int f = *flag;
    int nwaves = gridDim.x * 4;
    const int ngroups = N_EDGE / EPW;
    float b20 = b2_f[2 * lane], b21 = b2_f[2 * lane + 1];
    float wa = wa_f[lane];
    for (int g = blockIdx.x * 4 + wv; g < ngroups; g += nwaves) {
        int base = g * EPW;
        int rel[EPW], sub[EPW], obj[EPW], qi[EPW], tim[EPW];
#pragma unroll
        for (int e = 0; e < EPW; e++) {
            const int* ep = edges + (base + e) * 7;
            qi[e] = ep[0]; rel[e] = ep[2]; sub[e] = ep[4];
            obj[e] = ep[5]; tim[e] = ep[6];
        }
        float hs0[EPW], hs1[EPW];
#pragma unroll
        for (int e = 0; e < EPW; e++) {
            const float2* ar = (const float2*)(A_rel + rel[e] * 128);
            const float2* at = (const float2*)(A_timeb + tim[e] * 128);
            float2 a = ar[lane], t = at[lane];
            lds_h[wv][e][2 * lane]     = lrelu(a.x + t.x);
            lds_h[wv][e][2 * lane + 1] = lrelu(a.y + t.y);
            if (f) {
                ushort2 hv = ((const ushort2*)((const bf16*)hidden + sub[e] * 128))[lane];
                hs0[e] = bfbits2f(hv.x); hs1[e] = bfbits2f(hv.y);
            } else {
                float2 hv = ((const float2*)((const float*)hidden + sub[e] * 128))[lane];
                hs0[e] = hv.x; hs1[e] = hv.y;
            }
            lds_hs[wv][e][2 * lane]     = hs0[e];
            lds_hs[wv][e][2 * lane + 1] = hs1[e];
        }
        float acc0[EPW], acc1[EPW];
#pragma unroll
        for (int e = 0; e < EPW; e++) { acc0[e] = b20; acc1[e] = b21; }
        const float4* w0p = (const float4*)(W2T + (2 * lane) * 128);
        const float4* w1p = (const float4*)(W2T + (2 * lane + 1) * 128);
        for (int k4 = 0; k4 < 32; k4++) {
            float4 w0 = w0p[k4], w1 = w1p[k4];
#pragma unroll
            for (int e = 0; e < EPW; e++) {
                float4 h = ((const float4*)lds_h[wv][e])[k4];
                acc0[e] = dot4(h, w0, acc0[e]);
                acc1[e] = dot4(h, w1, acc1[e]);
            }
        }
        float hr0[EPW], hr1[EPW];
#pragma unroll
        for (int e = 0; e < EPW; e++) {
            const float2* rp = (const float2*)(rela_f + rel[e] * 128);
            float2 rv = rp[lane];
            hr0[e] = lrelu(acc0[e]) + rv.x;
            hr1[e] = lrelu(acc1[e]) + rv.y;
            lds_hr[wv][e][2 * lane]     = hr0[e];
            lds_hr[wv][e][2 * lane + 1] = hr1[e];
        }
        float att[EPW];
#pragma unroll
        for (int e = 0; e < EPW; e++) att[e] = Q_ws[qi[e] * 64 + lane];
        const float4* wrp = (const float4*)(WrT + lane * 128);
        const float4* wsp = (const float4*)(WsT + lane * 128);
        for (int k4 = 0; k4 < 32; k4++) {
            float4 w = wrp[k4], w2 = wsp[k4];
#pragma unroll
            for (int e = 0; e < EPW; e++) {
                float4 hr4 = ((const float4*)lds_hr[wv][e])[k4];
                float4 hs4 = ((const float4*)lds_hs[wv][e])[k4];
                att[e] = dot4(hr4, w, att[e]);
                att[e] = dot4(hs4, w2, att[e]);
            }
        }
        float ea[EPW];
#pragma unroll
        for (int e = 0; e < EPW; e++) {
            float a = lrelu(att[e]) * wa;
            a += __shfl_xor(a, 32); a += __shfl_xor(a, 16); a += __shfl_xor(a, 8);
            a += __shfl_xor(a, 4);  a += __shfl_xor(a, 2);  a += __shfl_xor(a, 1);
            ea[e] = __expf(a);
        }
#pragma unroll
        for (int e = 0; e < EPW; e++) {
            float v0 = ea[e] * (hs0[e] + hr0[e]);
            float v1 = ea[e] * (hs1[e] + hr1[e]);
            if (!f) {
                float* dst = (float*)dout + obj[e] * 128 + 2 * lane;
                unsafeAtomicAdd(dst,     v0);
                unsafeAtomicAdd(dst + 1, v1);
            } else {
                atom_pk_bf16((unsigned int*)dout + obj[e] * 64 + lane, v0, v1);
            }
            if (lane == 0) unsafeAtomicAdd(bot + obj[e], ea[e]);
        }
    }
}

// ---------- epilogue: out[n] = (up[n]/bot[n]) @ Wh; Wh cached in LDS, block loops nodes ----------
__global__ __launch_bounds__(256) void k_out(const float* __restrict__ up,
                      const float* __restrict__ bot,
                      const float* __restrict__ Wh_f, void* __restrict__ dout,
                      const int* __restrict__ flag, int tier_full) {
    __shared__ float wh[124][128];   // 63.5 KB: rows 0..123 cached; 124..127 from L2
    __shared__ float m[2][128];
    int tid = threadIdx.x;
    int half = tid >> 7, j = tid & 127;
    int f = *flag;
    for (int i = tid; i < 124 * 128; i += 256) ((float*)wh)[i] = Wh_f[i];
    __syncthreads();
    int nb = gridDim.x;
    int p0 = (int)(((long long)blockIdx.x * (N_NODE / 2)) / nb);
    int p1 = (int)(((long long)(blockIdx.x + 1) * (N_NODE / 2)) / nb);
    for (int p = p0; p < p1; ++p) {
        int n = p * 2 + half;
        float inv = 1.f / (bot[n] + 1e-5f);
        float num;
        if (tier_full) {
            num = up[(size_t)n * 128 + j];
        } else if (!f) {
            num = ((const float*)dout)[(size_t)n * 128 + j];
        } else {
            unsigned int w = ((const unsigned int*)dout)[(size_t)n * 64 + (j >> 1)];
            num = bfbits2f((unsigned short)((j & 1) ? (w >> 16) : (w & 0xffffu)));
        }
        m[half][j] = num * inv;
        __syncthreads();
        float acc = 0.f;
#pragma unroll 4
        for (int k = 0; k < 124; k++) acc = fmaf(m[half][k], wh[k][j], acc);
#pragma unroll
        for (int k = 124; k < 128; k++) acc = fmaf(m[half][k], Wh_f[k * 128 + j], acc);
        if (f) ((bf16*)dout)[(size_t)n * 128 + j] = __float2bfloat16(acc);
        else   ((float*)dout)[(size_t)n * 128 + j] = acc;
        __syncthreads();
    }
}

// ---------- launcher ----------
extern "C" void kernel_launch(void* const* d_in, const int* in_sizes, int n_in,
                              void* d_out, int out_size, void* d_ws, size_t ws_size,
                              hipStream_t stream) {
    const void* hidden = d_in[0];
    const void* rela   = d_in[1];
    const void* pe     = d_in[2];
    const void* W1     = d_in[3];
    const void* b1     = d_in[4];
    const void* W2     = d_in[5];
    const void* b2     = d_in[6];
    const void* Ws     = d_in[7];
    const void* Wr     = d_in[8];
    const void* Wqr    = d_in[9];
    const void* bqr    = d_in[10];
    const void* walpha = d_in[11];
    const void* Wh     = d_in[12];
    const int* q_rel   = (const int*)d_in[13];
    const int* edges   = (const int*)d_in[14];

    float* ws = (float*)d_ws;
    size_t off = 0;
    int*   flag    = (int*)(ws + off); off += 4;
    float* pool    = ws + off;
    float* rela_f  = pool;
    float* pe_f    = rela_f + SEG_RELA;
    float* W1_f    = pe_f + SEG_PE;
    float* b1_f    = W1_f + SEG_W1;
    float* W2T_f   = b1_f + SEG_B1;
    float* b2_f    = W2T_f + SEG_W2T;
    float* WsT_f   = b2_f + SEG_B2;
    float* Ws_f    = WsT_f + SEG_WST;
    float* WrT_f   = Ws_f + SEG_WS;
    float* WqrT_f  = WrT_f + SEG_WRT;
    float* bqr_f   = WqrT_f + SEG_WQRT;
    float* wa_f    = bqr_f + SEG_BQR;
    float* Wh_f    = wa_f + SEG_WA;
    off += POOL_TOTAL;
    float* A_rel   = ws + off; off += 401 * 128;
    float* A_timeb = ws + off; off += 1000 * 128;
    float* Q_ws    = ws + off; off += N_QUERY * 64;
    float* bot     = ws + off; off += N_NODE;
    short* W2pk    = (short*)(ws + off); off += 8192;
    short* Wrpk    = (short*)(ws + off); off += 4096;
    unsigned short* relcat = (unsigned short*)(ws + off); off += 401 * 128;   // 401*256 bf16
    unsigned short* atimb  = (unsigned short*)(ws + off); off += 1000 * 64;   // 1000*128 bf16
    unsigned short* S_b    = (unsigned short*)(ws + off); off += (size_t)N_NODE * 32; // 50000*64 bf16
    float* up      = ws + off; off += (size_t)N_NODE * 128;
    int*   perm    = (int*)(ws + off); off += N_EDGE;
    int*   cnt     = (int*)(ws + off); off += N_NODE + 32;
    int*   cur     = (int*)(ws + off); off += N_NODE + 32;
    size_t full_floats = off;   // ~9.46M floats = 37.85 MB (proven ws >= 39.6 MB)

    int tier_full = (ws_size >= full_floats * sizeof(float)) ? 1 : 0;

    k_detect<<<1, 1, 0, stream>>>((const unsigned int*)pe, flag);
    k_zero<<<2048, 256, 0, stream>>>((unsigned int*)d_out, out_size, flag, bot, up, cnt, tier_full);
    k_convert<<<(POOL_TOTAL + 255) / 256, 256, 0, stream>>>(
        rela, pe, W1, b1, W2, b2, Ws, Wr, Wqr, bqr, walpha, Wh, flag, pool);
    k_arel<<<401, 128, 0, stream>>>(rela_f, W1_f, A_rel, relcat);
    k_atime<<<1000, 128, 0, stream>>>(pe_f, W1_f, b1_f, A_timeb, atimb);
    k_qws<<<N_QUERY / 4, 256, 0, stream>>>(rela_f, q_rel, bqr_f, WqrT_f, Q_ws);

    if (tier_full) {
        k_pack<<<96, 256, 0, stream>>>(W2T_f, WrT_f, W2pk, Wrpk);
        k_snode<<<1024, 256, 0, stream>>>(hidden, Ws_f, flag, S_b);
        k_hist<<<1024, 256, 0, stream>>>(edges, cnt);
        k_scan<<<1, SCAN_T, 0, stream>>>(cnt, cur);
        k_scat<<<1024, 256, 0, stream>>>(edges, cur, perm);
        // 512 blocks = 2 blocks/CU x 256 CU at VGPR~200: whole grid resident in one batch
        k_edge_s<<<512, 256, 0, stream>>>(edges, perm, hidden, relcat, atimb, W2pk, Wrpk,
                                          b2_f, S_b, Q_ws, wa_f, flag, up, bot);
    } else {
        k_edge_c<<<1536, 256, 0, stream>>>(edges, hidden, rela_f, A_rel, A_timeb,
                                           W2T_f, WrT_f, WsT_f, b2_f, Q_ws, wa_f,
                                           flag, bot, d_out);
    }

    k_out<<<500, 256, 0, stream>>>(up, bot, Wh_f, d_out, flag, tier_full);
}

// Round 12
// 843.406 us; speedup vs baseline: 1.3391x; 1.2526x over previous
//
#include <hip/hip_runtime.h>
#include <hip/hip_bf16.h>

typedef __hip_bfloat16 bf16;
typedef __attribute__((ext_vector_type(8))) short bf16x8;
typedef __attribute__((ext_vector_type(4))) float f32x4;

#define N_NODE   50000
#define N_EDGE   800000
#define N_QUERY  512
#define EPW      8

__device__ __forceinline__ float bfbits2f(unsigned short u) {
    return __uint_as_float(((unsigned)u) << 16);
}
__device__ __forceinline__ unsigned short f2bfbits(float f) {
    unsigned int u = __float_as_uint(f);
    return (unsigned short)((u + 0x7fffu + ((u >> 16) & 1u)) >> 16);  // RNE
}
__device__ __forceinline__ float lrelu(float x) { return x > 0.f ? x : 0.01f * x; }
__device__ __forceinline__ float dot4(float4 a, float4 b, float acc) {
    acc = fmaf(a.x, b.x, acc); acc = fmaf(a.y, b.y, acc);
    acc = fmaf(a.z, b.z, acc); acc = fmaf(a.w, b.w, acc);
    return acc;
}
// async global->LDS DMA: per-lane 4B from per-lane global addr into (base + lane*4)
__device__ __forceinline__ void gld_lds4(const void* g, void* l) {
    __builtin_amdgcn_global_load_lds(
        (const __attribute__((address_space(1))) void*)g,
        (__attribute__((address_space(3))) void*)l, 4, 0, 0);
}
__device__ __forceinline__ void atom_pk_bf16(unsigned int* addr, float a0, float a1) {
    unsigned int old = *((volatile unsigned int*)addr);
    while (true) {
        float f0 = bfbits2f((unsigned short)(old & 0xffffu)) + a0;
        float f1 = bfbits2f((unsigned short)(old >> 16)) + a1;
        unsigned int nv = (unsigned int)f2bfbits(f0) | ((unsigned int)f2bfbits(f1) << 16);
        unsigned int prev = atomicCAS(addr, old, nv);
        if (prev == old) break;
        old = prev;
    }
}

// ---------- dtype detection (pe[0] word: fp32 -> 0x00000000, bf16 -> 0x3F800000) ----------
__global__ void k_detect(const unsigned int* __restrict__ pe_raw, int* __restrict__ flag) {
    *flag = (pe_raw[0] != 0u) ? 1 : 0;   // 1 = bf16 inputs, 0 = fp32 inputs
}

// ---------- zero accumulators (+ sort histogram) ----------
__global__ void k_zero(unsigned int* __restrict__ out_w, int out_elems,
                       const int* __restrict__ flag,
                       float* __restrict__ bot, float* __restrict__ up,
                       int* __restrict__ cnt, int tier_full) {
    int f = *flag;
    int stride = gridDim.x * blockDim.x;
    int tid = blockIdx.x * blockDim.x + threadIdx.x;
    for (int i = tid; i < N_NODE; i += stride) bot[i] = 0.f;
    if (tier_full) {
        for (int i = tid; i < N_NODE * 128; i += stride) up[i] = 0.f;
        for (int i = tid; i < N_NODE + 32; i += stride) cnt[i] = 0;
    } else {
        int out_words = f ? (out_elems >> 1) : out_elems;
        for (int i = tid; i < out_words; i += stride) out_w[i] = 0u;
    }
}

// ---------- counting sort of edges by obj: hist -> scan -> scatter ----------
__global__ void k_hist(const int* __restrict__ edges, int* __restrict__ cnt) {
    int stride = gridDim.x * blockDim.x;
    for (int i = blockIdx.x * blockDim.x + threadIdx.x; i < N_EDGE; i += stride)
        atomicAdd(&cnt[edges[i * 7 + 5]], 1);
}

#define SCAN_T 1024
#define SCAN_C 49   // 1024*49 = 50176 >= N_NODE
__global__ void k_scan(const int* __restrict__ cnt, int* __restrict__ cur) {
    __shared__ int part[SCAN_T];
    int t = threadIdx.x;
    int beg = t * SCAN_C;
    int s = 0;
    for (int i = 0; i < SCAN_C; i++) {
        int idx = beg + i;
        if (idx < N_NODE) s += cnt[idx];
    }
    part[t] = s;
    __syncthreads();
    for (int d = 1; d < SCAN_T; d <<= 1) {
        int v = (t >= d) ? part[t - d] : 0;
        __syncthreads();
        part[t] += v;
        __syncthreads();
    }
    int run = (t == 0) ? 0 : part[t - 1];
    for (int i = 0; i < SCAN_C; i++) {
        int idx = beg + i;
        if (idx < N_NODE) { cur[idx] = run; run += cnt[idx]; }
    }
}

__global__ void k_scat(const int* __restrict__ edges, int* __restrict__ cur,
                       int* __restrict__ perm) {
    int stride = gridDim.x * blockDim.x;
    for (int i = blockIdx.x * blockDim.x + threadIdx.x; i < N_EDGE; i += stride) {
        int obj = edges[i * 7 + 5];
        int pos = atomicAdd(&cur[obj], 1);
        perm[pos] = i;
    }
}

// ---------- convert all small tensors to fp32 pool (transposes W2/Ws/Wr/Wqr) ----------
#define SEG_RELA   51328
#define SEG_PE     32000
#define SEG_W1     20480
#define SEG_B1     128
#define SEG_W2T    16384
#define SEG_B2     128
#define SEG_WST    8192
#define SEG_WS     8192
#define SEG_WRT    8192
#define SEG_WQRT   8192
#define SEG_BQR    64
#define SEG_WA     64
#define SEG_WH     16384
#define POOL_TOTAL (SEG_RELA+SEG_PE+SEG_W1+SEG_B1+SEG_W2T+SEG_B2+SEG_WST+SEG_WS+SEG_WRT+SEG_WQRT+SEG_BQR+SEG_WA+SEG_WH)

__global__ void k_convert(const void* rela, const void* pe, const void* W1, const void* b1,
                          const void* W2, const void* b2, const void* Ws, const void* Wr,
                          const void* Wqr, const void* bqr, const void* walpha, const void* Wh,
                          const int* __restrict__ flag, float* __restrict__ pool) {
    int idx = blockIdx.x * blockDim.x + threadIdx.x;
    int f = *flag;
    auto ld = [&](const void* p, int i) -> float {
        return f ? __bfloat162float(((const bf16*)p)[i]) : ((const float*)p)[i];
    };
    int i = idx;
    if (i < SEG_RELA) { pool[idx] = ld(rela, i); return; } i -= SEG_RELA;
    if (i < SEG_PE)   { pool[idx] = ld(pe, i); return; }   i -= SEG_PE;
    if (i < SEG_W1)   { pool[idx] = ld(W1, i); return; }   i -= SEG_W1;
    if (i < SEG_B1)   { pool[idx] = ld(b1, i); return; }   i -= SEG_B1;
    if (i < SEG_W2T)  { pool[idx] = ld(W2, (i & 127) * 128 + (i >> 7)); return; } i -= SEG_W2T;
    if (i < SEG_B2)   { pool[idx] = ld(b2, i); return; }   i -= SEG_B2;
    if (i < SEG_WST)  { pool[idx] = ld(Ws,  (i & 127) * 64 + (i >> 7)); return; } i -= SEG_WST;
    if (i < SEG_WS)   { pool[idx] = ld(Ws, i); return; }   i -= SEG_WS;
    if (i < SEG_WRT)  { pool[idx] = ld(Wr,  (i & 127) * 64 + (i >> 7)); return; } i -= SEG_WRT;
    if (i < SEG_WQRT) { pool[idx] = ld(Wqr, (i & 127) * 64 + (i >> 7)); return; } i -= SEG_WQRT;
    if (i < SEG_BQR)  { pool[idx] = ld(bqr, i); return; }  i -= SEG_BQR;
    if (i < SEG_WA)   { pool[idx] = ld(walpha, i); return; } i -= SEG_WA;
    if (i < SEG_WH)   { pool[idx] = ld(Wh, i); return; }
}

// ---------- pack W2/Wr into MFMA B-fragment order (bf16) ----------
__global__ void k_pack(const float* __restrict__ W2T_f, const float* __restrict__ WrT_f,
                       short* __restrict__ W2pk, short* __restrict__ Wrpk) {
    int idx = blockIdx.x * blockDim.x + threadIdx.x;
    if (idx < 16384) {
        int j = idx & 7, lane = (idx >> 3) & 63, kb = (idx >> 9) & 3, nt = idx >> 11;
        int k = kb * 32 + (lane >> 4) * 8 + j, n = nt * 16 + (lane & 15);
        W2pk[idx] = (short)f2bfbits(W2T_f[n * 128 + k]);
    } else if (idx < 16384 + 8192) {
        int i2 = idx - 16384;
        int j = i2 & 7, lane = (i2 >> 3) & 63, kb = (i2 >> 9) & 3, nt = i2 >> 11;
        int k = kb * 32 + (lane >> 4) * 8 + j, n = nt * 16 + (lane & 15);
        Wrpk[i2] = (short)f2bfbits(WrT_f[n * 128 + k]);
    }
}

// ---------- precompute tables ----------
__global__ void k_arel(const float* __restrict__ rela_f, const float* __restrict__ W1_f,
                       float* __restrict__ A_rel, unsigned short* __restrict__ relcat) {
    __shared__ float ld[128];
    int r = blockIdx.x, j = threadIdx.x;
    float rv = rela_f[r * 128 + j];
    ld[j] = rv;
    __syncthreads();
    float acc = 0.f;
    for (int k = 0; k < 128; k++) acc = fmaf(ld[k], W1_f[k * 128 + j], acc);
    A_rel[r * 128 + j] = acc;
    relcat[r * 256 + j] = f2bfbits(acc);
    relcat[r * 256 + 128 + j] = f2bfbits(rv);
}

__global__ void k_atime(const float* __restrict__ pe_f, const float* __restrict__ W1_f,
                        const float* __restrict__ b1_f, float* __restrict__ A_timeb,
                        unsigned short* __restrict__ atimb) {
    __shared__ float ld[32];
    int t = blockIdx.x, j = threadIdx.x;
    if (j < 32) ld[j] = pe_f[t * 32 + j];
    __syncthreads();
    float acc = b1_f[j];
    for (int k = 0; k < 32; k++) acc = fmaf(ld[k], W1_f[(128 + k) * 128 + j], acc);
    A_timeb[t * 128 + j] = acc;
    atimb[t * 128 + j] = f2bfbits(acc);
}

__global__ void k_qws(const float* __restrict__ rela_f, const int* __restrict__ q_rel,
                      const float* __restrict__ bqr_f, const float* __restrict__ WqrT_f,
                      float* __restrict__ Q_ws) {
    alignas(16) __shared__ float qrow[4][128];
    int wv = threadIdx.x >> 6, lane = threadIdx.x & 63;
    int q = blockIdx.x * 4 + wv;
    int qr = q_rel[q];
    const float2* rp = (const float2*)(rela_f + qr * 128);
    float2 rv = rp[lane];
    qrow[wv][2 * lane] = rv.x;
    qrow[wv][2 * lane + 1] = rv.y;
    __syncthreads();
    const float4* wp = (const float4*)(WqrT_f + lane * 128);
    const float4* qp4 = (const float4*)qrow[wv];
    float acc = bqr_f[lane];
    for (int k4 = 0; k4 < 32; k4++) acc = dot4(qp4[k4], wp[k4], acc);
    Q_ws[q * 64 + lane] = acc;
}

// S_b bf16 [50000][64] = hidden[n] . Ws  (full tier only)
__global__ __launch_bounds__(256) void k_snode(const void* __restrict__ hidden,
                        const float* __restrict__ Ws_f,   // [128][64] fp32 (non-transposed)
                        const int* __restrict__ flag, unsigned short* __restrict__ S_b) {
    __shared__ float ws_lds[128][64];                 // 32 KB
    alignas(16) __shared__ float hrow[4][128];
    int tid = threadIdx.x;
    int wv = tid >> 6, lane = tid & 63;
    int f = *flag;
    for (int i = tid; i < 8192; i += 256) ((float*)ws_lds)[i] = Ws_f[i];
    __syncthreads();
    int nb = gridDim.x;
    int q0 = (int)(((long long)blockIdx.x * (N_NODE / 4)) / nb);
    int q1 = (int)(((long long)(blockIdx.x + 1) * (N_NODE / 4)) / nb);
    for (int qg = q0; qg < q1; ++qg) {
        int n = qg * 4 + wv;
        if (f) {
            ushort2 hv = ((const ushort2*)((const bf16*)hidden + (size_t)n * 128))[lane];
            hrow[wv][2 * lane]     = bfbits2f(hv.x);
            hrow[wv][2 * lane + 1] = bfbits2f(hv.y);
        } else {
            float2 hv = ((const float2*)((const float*)hidden + (size_t)n * 128))[lane];
            hrow[wv][2 * lane]     = hv.x;
            hrow[wv][2 * lane + 1] = hv.y;
        }
        // hrow is wave-private: no block barrier needed
        float acc = 0.f;
#pragma unroll 8
        for (int k = 0; k < 128; k++) acc = fmaf(hrow[wv][k], ws_lds[k][lane], acc);
        S_b[(size_t)n * 64 + lane] = f2bfbits(acc);
    }
}

// ---------- SCATTER edge kernel: static spans, MFMA, async hidden DMA, run-merged flush ----------
// No occupancy attribute: natural VGPR ~176 -> 2 blocks/CU. Grid is sized to 512 = 2x256 CU
// so the whole grid is resident (R7 lesson: forcing 3 waves/EU spills to VGPR 84, 1.16 GB FETCH).
// R11 lesson: this exact body is a compiler-schedule local optimum (409us); additive prefetch
// or pre-gather edits regress it 50%+. Do not perturb without inline-asm-level control.
__global__ __launch_bounds__(256) void k_edge_s(
        const int* __restrict__ edges, const int* __restrict__ perm,
        const void* __restrict__ hidden,
        const unsigned short* __restrict__ relcat,   // [r][256] A_rel|rela bf16
        const unsigned short* __restrict__ atimb,    // [t][128] bf16
        const short* __restrict__ W2pk, const short* __restrict__ Wrpk,
        const float* __restrict__ b2_f, const unsigned short* __restrict__ S_b,
        const float* __restrict__ Q_ws, const float* __restrict__ wa_f,
        const int* __restrict__ flag,
        float* __restrict__ up, float* __restrict__ bot) {
    alignas(16) __shared__ short buf[4][16][136];   // wave-private h -> hr buffer
    alignas(16) __shared__ float hid[4][16][128];   // wave-private staged hidden rows (raw)
    int wv = threadIdx.x >> 6, lane = threadIdx.x & 63;
    int c = lane & 15, q = lane >> 4;
    int f = *flag;
    const int ngroups = N_EDGE / 16;  // 50000 exact

    // contiguous span of sorted groups per wave -> runs merge across groups
    int wvid = blockIdx.x * 4 + wv;
    int nw = gridDim.x * 4;
    int g0 = (int)(((long long)wvid * ngroups) / nw);
    int g1 = (int)(((long long)(wvid + 1) * ngroups) / nw);

    short (*bw)[136] = buf[wv];
    float (*hw)[128] = hid[wv];

    int cur_obj = -1;
    float vacc0 = 0.f, vacc1 = 0.f, eacc = 0.f;

    for (int g = g0; g < g1; ++g) {
        int base = g * 16;

        // lane e (<16) holds (perm'd) edge e's packed fields
        int w0 = 0, w1 = 0, w2 = 0;
        if (lane < 16) {
            int ed = perm[base + lane];
            const int* ep = edges + ed * 7;
            w0 = ep[4] | (ep[0] << 16);   // sub | qi<<16   (both < 65536)
            w1 = ep[2] | (ep[6] << 16);   // rel | tim<<16
            w2 = ep[5];                   // obj
        }

        // issue async hidden-row DMA for all 16 edges; consumed in the scatter phase.
        if (f) {
#pragma unroll
            for (int e = 0; e < 16; e++) {
                int sub_e = __shfl(w0, e) & 0xffff;
                const char* src = (const char*)hidden + (size_t)sub_e * 256 + lane * 4;
                gld_lds4(src, &hw[e][0]);               // 256B row (bf16)
            }
        } else {
#pragma unroll
            for (int e = 0; e < 16; e++) {
                int sub_e = __shfl(w0, e) & 0xffff;
                const char* src = (const char*)hidden + (size_t)sub_e * 512 + lane * 4;
                gld_lds4(src,       &hw[e][0]);         // floats 0..63
                gld_lds4(src + 256, &hw[e][64]);        // floats 64..127
            }
        }

        // stage h = lrelu(A_rel + A_timeb) (bf16 coalesced reads) into LDS
#pragma unroll
        for (int e = 0; e < 16; e++) {
            int w1e = __shfl(w1, e);
            int rel_e = w1e & 0xffff, tim_e = w1e >> 16;
            ushort2 a = ((const ushort2*)(relcat + rel_e * 256))[lane];
            ushort2 t = ((const ushort2*)(atimb + tim_e * 128))[lane];
            float h0 = lrelu(bfbits2f(a.x) + bfbits2f(t.x));
            float h1 = lrelu(bfbits2f(a.y) + bfbits2f(t.y));
            *((unsigned int*)&bw[e][2 * lane]) =
                (unsigned)f2bfbits(h0) | ((unsigned)f2bfbits(h1) << 16);
        }

        bf16x8 hf[4];
#pragma unroll
        for (int kb = 0; kb < 4; kb++)
            hf[kb] = *((const bf16x8*)&bw[c][kb * 32 + q * 8]);

        // per-lane row metadata packed (rel=w14&0xffff, sub=w04&0xffff, qi=w04>>16)
        int w04[4], w14[4];
#pragma unroll
        for (int r = 0; r < 4; r++) {
            w14[r] = __shfl(w1, q * 4 + r);
            w04[r] = __shfl(w0, q * 4 + r);
        }

        // hr = lrelu(h@W2 + b2) + rel_e  -> buf (fixup folded into epilogue)
#pragma unroll
        for (int nt = 0; nt < 8; nt++) {
            f32x4 acc = {0.f, 0.f, 0.f, 0.f};
#pragma unroll
            for (int kb = 0; kb < 4; kb++) {
                bf16x8 bfr = *((const bf16x8*)(W2pk + (((nt * 4 + kb) * 64) + lane) * 8));
                acc = __builtin_amdgcn_mfma_f32_16x16x32_bf16(hf[kb], bfr, acc, 0, 0, 0);
            }
            int colg = nt * 16 + c;
            float b2v = b2_f[colg];
#pragma unroll
            for (int r = 0; r < 4; r++) {
                float rv = bfbits2f(relcat[(w14[r] & 0xffff) * 256 + 128 + colg]);
                bw[q * 4 + r][colg] = (short)f2bfbits(lrelu(acc[r] + b2v) + rv);
            }
        }

        // reload fragments (now hr) into the same registers
#pragma unroll
        for (int kb = 0; kb < 4; kb++)
            hf[kb] = *((const bf16x8*)&bw[c][kb * 32 + q * 8]);

        // att = lrelu(S_node + Q_ws + hr@Wr) . w_alpha
        float asum[4] = {0.f, 0.f, 0.f, 0.f};
#pragma unroll
        for (int nt = 0; nt < 4; nt++) {
            f32x4 acc = {0.f, 0.f, 0.f, 0.f};
#pragma unroll
            for (int kb = 0; kb < 4; kb++) {
                bf16x8 bfr = *((const bf16x8*)(Wrpk + (((nt * 4 + kb) * 64) + lane) * 8));
                acc = __builtin_amdgcn_mfma_f32_16x16x32_bf16(hf[kb], bfr, acc, 0, 0, 0);
            }
            int colg = nt * 16 + c;
            float wav = wa_f[colg & 63];
#pragma unroll
            for (int r = 0; r < 4; r++) {
                float av = acc[r] + bfbits2f(S_b[(w04[r] & 0xffff) * 64 + colg])
                         + Q_ws[(w04[r] >> 16) * 64 + colg];
                asum[r] += lrelu(av) * wav;
            }
        }
        float ea[4];
#pragma unroll
        for (int r = 0; r < 4; r++) {
            float a = asum[r];
            a += __shfl_xor(a, 1); a += __shfl_xor(a, 2);
            a += __shfl_xor(a, 4); a += __shfl_xor(a, 8);
            ea[r] = __expf(a);
        }

        // drain the hidden DMA (long since issued), then scatter purely from LDS
        asm volatile("s_waitcnt vmcnt(0)" ::: "memory");
        __builtin_amdgcn_sched_barrier(0);

        // run-merged scatter: edges arrive obj-sorted; flush once per run
#pragma unroll
        for (int e = 0; e < 16; e++) {
            float eav = __shfl(ea[e & 3], (e >> 2) * 16);
            int obj_e = __builtin_amdgcn_readfirstlane(__shfl(w2, e));
            unsigned int pk = *((const unsigned int*)&bw[e][2 * lane]);
            float hr0 = bfbits2f((unsigned short)(pk & 0xffffu));
            float hr1 = bfbits2f((unsigned short)(pk >> 16));
            float hs0, hs1;
            if (f) {
                unsigned int hb = ((const unsigned int*)&hw[e][0])[lane];
                hs0 = bfbits2f((unsigned short)(hb & 0xffffu));
                hs1 = bfbits2f((unsigned short)(hb >> 16));
            } else {
                float2 hv = ((const float2*)&hw[e][0])[lane];
                hs0 = hv.x; hs1 = hv.y;
            }
            float v0 = eav * (hs0 + hr0);
            float v1 = eav * (hs1 + hr1);
            if (obj_e != cur_obj) {
                if (cur_obj >= 0) {
                    float* dst = up + cur_obj * 128 + 2 * lane;
                    unsafeAtomicAdd(dst,     vacc0);
                    unsafeAtomicAdd(dst + 1, vacc1);
                    if (lane == 0) unsafeAtomicAdd(bot + cur_obj, eacc);
                }
                cur_obj = obj_e;
                vacc0 = v0; vacc1 = v1; eacc = eav;
            } else {
                vacc0 += v0; vacc1 += v1; eacc += eav;
            }
        }
    }
    // final flush of the span's trailing run
    if (cur_obj >= 0) {
        float* dst = up + cur_obj * 128 + 2 * lane;
        unsafeAtomicAdd(dst,     vacc0);
        unsafeAtomicAdd(dst + 1, vacc1);
        if (lane == 0) unsafeAtomicAdd(bot + cur_obj, eacc);
    }
}

// ---------- COMPACT-tier fallback (atomics into d_out) ----------
__global__ __launch_bounds__(256) void k_edge_c(
        const int* __restrict__ edges, const void* __restrict__ hidden,
        const float* __restrict__ rela_f,
        const float* __restrict__ A_rel, const float* __restrict__ A_timeb,
        const float* __restrict__ W2T, const float* __restrict__ WrT,
        const float* __restrict__ WsT, const float* __restrict__ b2_f,
        const float* __restrict__ Q_ws, const float* __restrict__ wa_f,
        const int* __restrict__ flag,
        float* __restrict__ bot, void* __restrict__ dout) {
    alignas(16) __shared__ float lds_h[4][EPW][128];
    alignas(16) __shared__ float lds_hr[4][EPW][128];
    alignas(16) __shared__ float lds_hs[4][EPW][128];
    int wv = threadIdx.x >> 6, lane = threadIdx.x & 63;
    int f = *flag;
    int nwaves = gridDim.x * 4;
    const int ngroups = N_EDGE / EPW;
    float b20 = b2_f[2 * lane], b21 = b2_f[2 * lane + 1];
    float wa = wa_f[lane];
    for (int g = blockIdx.x * 4 + wv; g < ngroups; g += nwaves) {
        int base = g * EPW;
        int rel[EPW], sub[EPW], obj[EPW], qi[EPW], tim[EPW];
#pragma unroll
        for (int e = 0; e < EPW; e++) {
            const int* ep = edges + (base + e) * 7;
            qi[e] = ep[0]; rel[e] = ep[2]; sub[e] = ep[4];
            obj[e] = ep[5]; tim[e] = ep[6];
        }
        float hs0[EPW], hs1[EPW];
#pragma unroll
        for (int e = 0; e < EPW; e++) {
            const float2* ar = (const float2*)(A_rel + rel[e] * 128);
            const float2* at = (const float2*)(A_timeb + tim[e] * 128);
            float2 a = ar[lane], t = at[lane];
            lds_h[wv][e][2 * lane]     = lrelu(a.x + t.x);
            lds_h[wv][e][2 * lane + 1] = lrelu(a.y + t.y);
            if (f) {
                ushort2 hv = ((const ushort2*)((const bf16*)hidden + sub[e] * 128))[lane];
                hs0[e] = bfbits2f(hv.x); hs1[e] = bfbits2f(hv.y);
            } else {
                float2 hv = ((const float2*)((const float*)hidden + sub[e] * 128))[lane];
                hs0[e] = hv.x; hs1[e] = hv.y;
            }
            lds_hs[wv][e][2 * lane]     = hs0[e];
            lds_hs[wv][e][2 * lane + 1] = hs1[e];
        }
        float acc0[EPW], acc1[EPW];
#pragma unroll
        for (int e = 0; e < EPW; e++) { acc0[e] = b20; acc1[e] = b21; }
        const float4* w0p = (const float4*)(W2T + (2 * lane) * 128);
        const float4* w1p = (const float4*)(W2T + (2 * lane + 1) * 128);
        for (int k4 = 0; k4 < 32; k4++) {
            float4 w0 = w0p[k4], w1 = w1p[k4];
#pragma unroll
            for (int e = 0; e < EPW; e++) {
                float4 h = ((const float4*)lds_h[wv][e])[k4];
                acc0[e] = dot4(h, w0, acc0[e]);
                acc1[e] = dot4(h, w1, acc1[e]);
            }
        }
        float hr0[EPW], hr1[EPW];
#pragma unroll
        for (int e = 0; e < EPW; e++) {
            const float2* rp = (const float2*)(rela_f + rel[e] * 128);
            float2 rv = rp[lane];
            hr0[e] = lrelu(acc0[e]) + rv.x;
            hr1[e] = lrelu(acc1[e]) + rv.y;
            lds_hr[wv][e][2 * lane]     = hr0[e];
            lds_hr[wv][e][2 * lane + 1] = hr1[e];
        }
        float att[EPW];
#pragma unroll
        for (int e = 0; e < EPW; e++) att[e] = Q_ws[qi[e] * 64 + lane];
        const float4* wrp = (const float4*)(WrT + lane * 128);
        const float4* wsp = (const float4*)(WsT + lane * 128);
        for (int k4 = 0; k4 < 32; k4++) {
            float4 w = wrp[k4], w2 = wsp[k4];
#pragma unroll
            for (int e = 0; e < EPW; e++) {
                float4 hr4 = ((const float4*)lds_hr[wv][e])[k4];
                float4 hs4 = ((const float4*)lds_hs[wv][e])[k4];
                att[e] = dot4(hr4, w, att[e]);
                att[e] = dot4(hs4, w2, att[e]);
            }
        }
        float ea[EPW];
#pragma unroll
        for (int e = 0; e < EPW; e++) {
            float a = lrelu(att[e]) * wa;
            a += __shfl_xor(a, 32); a += __shfl_xor(a, 16); a += __shfl_xor(a, 8);
            a += __shfl_xor(a, 4);  a += __shfl_xor(a, 2);  a += __shfl_xor(a, 1);
            ea[e] = __expf(a);
        }
#pragma unroll
        for (int e = 0; e < EPW; e++) {
            float v0 = ea[e] * (hs0[e] + hr0[e]);
            float v1 = ea[e] * (hs1[e] + hr1[e]);
            if (!f) {
                float* dst = (float*)dout + obj[e] * 128 + 2 * lane;
                unsafeAtomicAdd(dst,     v0);
                unsafeAtomicAdd(dst + 1, v1);
            } else {
                atom_pk_bf16((unsigned int*)dout + obj[e] * 64 + lane, v0, v1);
            }
            if (lane == 0) unsafeAtomicAdd(bot + obj[e], ea[e]);
        }
    }
}

// ---------- epilogue: out[n] = (up[n]/bot[n]) @ Wh; Wh cached in LDS, block loops nodes ----------
__global__ __launch_bounds__(256) void k_out(const float* __restrict__ up,
                      const float* __restrict__ bot,
                      const float* __restrict__ Wh_f, void* __restrict__ dout,
                      const int* __restrict__ flag, int tier_full) {
    __shared__ float wh[124][128];   // 63.5 KB: rows 0..123 cached; 124..127 from L2
    __shared__ float m[2][128];
    int tid = threadIdx.x;
    int half = tid >> 7, j = tid & 127;
    int f = *flag;
    for (int i = tid; i < 124 * 128; i += 256) ((float*)wh)[i] = Wh_f[i];
    __syncthreads();
    int nb = gridDim.x;
    int p0 = (int)(((long long)blockIdx.x * (N_NODE / 2)) / nb);
    int p1 = (int)(((long long)(blockIdx.x + 1) * (N_NODE / 2)) / nb);
    for (int p = p0; p < p1; ++p) {
        int n = p * 2 + half;
        float inv = 1.f / (bot[n] + 1e-5f);
        float num;
        if (tier_full) {
            num = up[(size_t)n * 128 + j];
        } else if (!f) {
            num = ((const float*)dout)[(size_t)n * 128 + j];
        } else {
            unsigned int w = ((const unsigned int*)dout)[(size_t)n * 64 + (j >> 1)];
            num = bfbits2f((unsigned short)((j & 1) ? (w >> 16) : (w & 0xffffu)));
        }
        m[half][j] = num * inv;
        __syncthreads();
        float acc = 0.f;
#pragma unroll 4
        for (int k = 0; k < 124; k++) acc = fmaf(m[half][k], wh[k][j], acc);
#pragma unroll
        for (int k = 124; k < 128; k++) acc = fmaf(m[half][k], Wh_f[k * 128 + j], acc);
        if (f) ((bf16*)dout)[(size_t)n * 128 + j] = __float2bfloat16(acc);
        else   ((float*)dout)[(size_t)n * 128 + j] = acc;
        __syncthreads();   // protect m before next iteration overwrites it
    }
}

// ---------- launcher ----------
extern "C" void kernel_launch(void* const* d_in, const int* in_sizes, int n_in,
                              void* d_out, int out_size, void* d_ws, size_t ws_size,
                              hipStream_t stream) {
    const void* hidden = d_in[0];
    const void* rela   = d_in[1];
    const void* pe     = d_in[2];
    const void* W1     = d_in[3];
    const void* b1     = d_in[4];
    const void* W2     = d_in[5];
    const void* b2     = d_in[6];
    const void* Ws     = d_in[7];
    const void* Wr     = d_in[8];
    const void* Wqr    = d_in[9];
    const void* bqr    = d_in[10];
    const void* walpha = d_in[11];
    const void* Wh     = d_in[12];
    const int* q_rel   = (const int*)d_in[13];
    const int* edges   = (const int*)d_in[14];

    float* ws = (float*)d_ws;
    size_t off = 0;
    int*   flag    = (int*)(ws + off); off += 4;
    float* pool    = ws + off;
    float* rela_f  = pool;
    float* pe_f    = rela_f + SEG_RELA;
    float* W1_f    = pe_f + SEG_PE;
    float* b1_f    = W1_f + SEG_W1;
    float* W2T_f   = b1_f + SEG_B1;
    float* b2_f    = W2T_f + SEG_W2T;
    float* WsT_f   = b2_f + SEG_B2;
    float* Ws_f    = WsT_f + SEG_WST;
    float* WrT_f   = Ws_f + SEG_WS;
    float* WqrT_f  = WrT_f + SEG_WRT;
    float* bqr_f   = WqrT_f + SEG_WQRT;
    float* wa_f    = bqr_f + SEG_BQR;
    float* Wh_f    = wa_f + SEG_WA;
    off += POOL_TOTAL;
    float* A_rel   = ws + off; off += 401 * 128;
    float* A_timeb = ws + off; off += 1000 * 128;
    float* Q_ws    = ws + off; off += N_QUERY * 64;
    float* bot     = ws + off; off += N_NODE;
    short* W2pk    = (short*)(ws + off); off += 8192;
    short* Wrpk    = (short*)(ws + off); off += 4096;
    unsigned short* relcat = (unsigned short*)(ws + off); off += 401 * 128;   // 401*256 bf16
    unsigned short* atimb  = (unsigned short*)(ws + off); off += 1000 * 64;   // 1000*128 bf16
    unsigned short* S_b    = (unsigned short*)(ws + off); off += (size_t)N_NODE * 32; // 50000*64 bf16
    float* up      = ws + off; off += (size_t)N_NODE * 128;
    int*   perm    = (int*)(ws + off); off += N_EDGE;
    int*   cnt     = (int*)(ws + off); off += N_NODE + 32;
    int*   cur     = (int*)(ws + off); off += N_NODE + 32;
    size_t full_floats = off;   // ~9.46M floats = 37.85 MB (proven ws >= 39.6 MB)

    int tier_full = (ws_size >= full_floats * sizeof(float)) ? 1 : 0;

    k_detect<<<1, 1, 0, stream>>>((const unsigned int*)pe, flag);
    k_zero<<<2048, 256, 0, stream>>>((unsigned int*)d_out, out_size, flag, bot, up, cnt, tier_full);
    k_convert<<<(POOL_TOTAL + 255) / 256, 256, 0, stream>>>(
        rela, pe, W1, b1, W2, b2, Ws, Wr, Wqr, bqr, walpha, Wh, flag, pool);
    k_arel<<<401, 128, 0, stream>>>(rela_f, W1_f, A_rel, relcat);
    k_atime<<<1000, 128, 0, stream>>>(pe_f, W1_f, b1_f, A_timeb, atimb);
    k_qws<<<N_QUERY / 4, 256, 0, stream>>>(rela_f, q_rel, bqr_f, WqrT_f, Q_ws);

    if (tier_full) {
        k_pack<<<96, 256, 0, stream>>>(W2T_f, WrT_f, W2pk, Wrpk);
        k_snode<<<1024, 256, 0, stream>>>(hidden, Ws_f, flag, S_b);
        k_hist<<<1024, 256, 0, stream>>>(edges, cnt);
        k_scan<<<1, SCAN_T, 0, stream>>>(cnt, cur);
        k_scat<<<1024, 256, 0, stream>>>(edges, cur, perm);
        // 512 blocks = 2 blocks/CU x 256 CU at VGPR=176: whole grid resident in one batch
        k_edge_s<<<512, 256, 0, stream>>>(edges, perm, hidden, relcat, atimb, W2pk, Wrpk,
                                          b2_f, S_b, Q_ws, wa_f, flag, up, bot);
    } else {
        k_edge_c<<<1536, 256, 0, stream>>>(edges, hidden, rela_f, A_rel, A_timeb,
                                           W2T_f, WrT_f, WsT_f, b2_f, Q_ws, wa_f,
                                           flag, bot, d_out);
    }

    k_out<<<500, 256, 0, stream>>>(up, bot, Wh_f, d_out, flag, tier_full);
}

// Round 13
// 765.261 us; speedup vs baseline: 1.4758x; 1.1021x over previous
//
#include <hip/hip_runtime.h>
#include <hip/hip_bf16.h>

typedef __hip_bfloat16 bf16;
typedef __attribute__((ext_vector_type(8))) short bf16x8;
typedef __attribute__((ext_vector_type(4))) float f32x4;

#define N_NODE   50000
#define N_EDGE   800000
#define N_QUERY  512
#define EPW      8

__device__ __forceinline__ float bfbits2f(unsigned short u) {
    return __uint_as_float(((unsigned)u) << 16);
}
__device__ __forceinline__ unsigned short f2bfbits(float f) {
    unsigned int u = __float_as_uint(f);
    return (unsigned short)((u + 0x7fffu + ((u >> 16) & 1u)) >> 16);  // RNE
}
__device__ __forceinline__ float lrelu(float x) { return x > 0.f ? x : 0.01f * x; }
__device__ __forceinline__ float dot4(float4 a, float4 b, float acc) {
    acc = fmaf(a.x, b.x, acc); acc = fmaf(a.y, b.y, acc);
    acc = fmaf(a.z, b.z, acc); acc = fmaf(a.w, b.w, acc);
    return acc;
}
// async global->LDS DMA: per-lane 4B from per-lane global addr into (base + lane*4)
__device__ __forceinline__ void gld_lds4(const void* g, void* l) {
    __builtin_amdgcn_global_load_lds(
        (const __attribute__((address_space(1))) void*)g,
        (__attribute__((address_space(3))) void*)l, 4, 0, 0);
}
__device__ __forceinline__ void atom_pk_bf16(unsigned int* addr, float a0, float a1) {
    unsigned int old = *((volatile unsigned int*)addr);
    while (true) {
        float f0 = bfbits2f((unsigned short)(old & 0xffffu)) + a0;
        float f1 = bfbits2f((unsigned short)(old >> 16)) + a1;
        unsigned int nv = (unsigned int)f2bfbits(f0) | ((unsigned int)f2bfbits(f1) << 16);
        unsigned int prev = atomicCAS(addr, old, nv);
        if (prev == old) break;
        old = prev;
    }
}

// ---------- dtype detection (pe[0] word: fp32 -> 0x00000000, bf16 -> 0x3F800000) ----------
__global__ void k_detect(const unsigned int* __restrict__ pe_raw, int* __restrict__ flag) {
    *flag = (pe_raw[0] != 0u) ? 1 : 0;   // 1 = bf16 inputs, 0 = fp32 inputs
}

// ---------- zero accumulators (compact-tier fallback only; full tier uses memset nodes) ----------
__global__ void k_zero(unsigned int* __restrict__ out_w, int out_elems,
                       const int* __restrict__ flag,
                       float* __restrict__ bot, float* __restrict__ up,
                       int* __restrict__ cnt, int tier_full) {
    int f = *flag;
    int stride = gridDim.x * blockDim.x;
    int tid = blockIdx.x * blockDim.x + threadIdx.x;
    for (int i = tid; i < N_NODE; i += stride) bot[i] = 0.f;
    if (tier_full) {
        for (int i = tid; i < N_NODE * 128; i += stride) up[i] = 0.f;
        for (int i = tid; i < N_NODE + 32; i += stride) cnt[i] = 0;
    } else {
        int out_words = f ? (out_elems >> 1) : out_elems;
        for (int i = tid; i < out_words; i += stride) out_w[i] = 0u;
    }
}

// ---------- counting sort of edges by obj: hist -> parallel scan -> scatter ----------
__global__ void k_hist(const int* __restrict__ edges, int* __restrict__ cnt) {
    int stride = gridDim.x * blockDim.x;
    for (int i = blockIdx.x * blockDim.x + threadIdx.x; i < N_EDGE; i += stride)
        atomicAdd(&cnt[edges[i * 7 + 5]], 1);
}

// parallel scan phase 1: 49 blocks x 1024; coalesced load, in-LDS inclusive scan,
// write block-local EXCLUSIVE prefix to cur, block total to tot[b].
__global__ __launch_bounds__(1024) void k_scan1(const int* __restrict__ cnt,
                                                int* __restrict__ cur,
                                                int* __restrict__ tot) {
    __shared__ int part[1024];
    int t = threadIdx.x;
    int idx = blockIdx.x * 1024 + t;
    int v = (idx < N_NODE) ? cnt[idx] : 0;
    part[t] = v;
    __syncthreads();
    for (int d = 1; d < 1024; d <<= 1) {
        int tmp = (t >= d) ? part[t - d] : 0;
        __syncthreads();
        part[t] += tmp;
        __syncthreads();
    }
    if (idx < N_NODE) cur[idx] = part[t] - v;     // exclusive, block-local
    if (t == 1023) tot[blockIdx.x] = part[1023];
}

// parallel scan phase 2: 49 blocks x 1024; add global offset sum(tot[0..b)).
__global__ __launch_bounds__(1024) void k_scan2(const int* __restrict__ tot,
                                                int* __restrict__ cur) {
    __shared__ int offs;
    if (threadIdx.x == 0) {
        int s = 0;
        for (int i = 0; i < (int)blockIdx.x; i++) s += tot[i];
        offs = s;
    }
    __syncthreads();
    int idx = blockIdx.x * 1024 + threadIdx.x;
    if (idx < N_NODE) cur[idx] += offs;
}

__global__ void k_scat(const int* __restrict__ edges, int* __restrict__ cur,
                       int* __restrict__ perm) {
    int stride = gridDim.x * blockDim.x;
    for (int i = blockIdx.x * blockDim.x + threadIdx.x; i < N_EDGE; i += stride) {
        int obj = edges[i * 7 + 5];
        int pos = atomicAdd(&cur[obj], 1);
        perm[pos] = i;
    }
}

// ---------- convert all small tensors to fp32 pool (transposes W2/Ws/Wr/Wqr) ----------
#define SEG_RELA   51328
#define SEG_PE     32000
#define SEG_W1     20480
#define SEG_B1     128
#define SEG_W2T    16384
#define SEG_B2     128
#define SEG_WST    8192
#define SEG_WS     8192
#define SEG_WRT    8192
#define SEG_WQRT   8192
#define SEG_BQR    64
#define SEG_WA     64
#define SEG_WH     16384
#define POOL_TOTAL (SEG_RELA+SEG_PE+SEG_W1+SEG_B1+SEG_W2T+SEG_B2+SEG_WST+SEG_WS+SEG_WRT+SEG_WQRT+SEG_BQR+SEG_WA+SEG_WH)

__global__ void k_convert(const void* rela, const void* pe, const void* W1, const void* b1,
                          const void* W2, const void* b2, const void* Ws, const void* Wr,
                          const void* Wqr, const void* bqr, const void* walpha, const void* Wh,
                          const int* __restrict__ flag, float* __restrict__ pool) {
    int idx = blockIdx.x * blockDim.x + threadIdx.x;
    int f = *flag;
    auto ld = [&](const void* p, int i) -> float {
        return f ? __bfloat162float(((const bf16*)p)[i]) : ((const float*)p)[i];
    };
    int i = idx;
    if (i < SEG_RELA) { pool[idx] = ld(rela, i); return; } i -= SEG_RELA;
    if (i < SEG_PE)   { pool[idx] = ld(pe, i); return; }   i -= SEG_PE;
    if (i < SEG_W1)   { pool[idx] = ld(W1, i); return; }   i -= SEG_W1;
    if (i < SEG_B1)   { pool[idx] = ld(b1, i); return; }   i -= SEG_B1;
    if (i < SEG_W2T)  { pool[idx] = ld(W2, (i & 127) * 128 + (i >> 7)); return; } i -= SEG_W2T;
    if (i < SEG_B2)   { pool[idx] = ld(b2, i); return; }   i -= SEG_B2;
    if (i < SEG_WST)  { pool[idx] = ld(Ws,  (i & 127) * 64 + (i >> 7)); return; } i -= SEG_WST;
    if (i < SEG_WS)   { pool[idx] = ld(Ws, i); return; }   i -= SEG_WS;
    if (i < SEG_WRT)  { pool[idx] = ld(Wr,  (i & 127) * 64 + (i >> 7)); return; } i -= SEG_WRT;
    if (i < SEG_WQRT) { pool[idx] = ld(Wqr, (i & 127) * 64 + (i >> 7)); return; } i -= SEG_WQRT;
    if (i < SEG_BQR)  { pool[idx] = ld(bqr, i); return; }  i -= SEG_BQR;
    if (i < SEG_WA)   { pool[idx] = ld(walpha, i); return; } i -= SEG_WA;
    if (i < SEG_WH)   { pool[idx] = ld(Wh, i); return; }
}

// ---------- pack W2/Wr into MFMA B-fragment order (bf16) ----------
__global__ void k_pack(const float* __restrict__ W2T_f, const float* __restrict__ WrT_f,
                       short* __restrict__ W2pk, short* __restrict__ Wrpk) {
    int idx = blockIdx.x * blockDim.x + threadIdx.x;
    if (idx < 16384) {
        int j = idx & 7, lane = (idx >> 3) & 63, kb = (idx >> 9) & 3, nt = idx >> 11;
        int k = kb * 32 + (lane >> 4) * 8 + j, n = nt * 16 + (lane & 15);
        W2pk[idx] = (short)f2bfbits(W2T_f[n * 128 + k]);
    } else if (idx < 16384 + 8192) {
        int i2 = idx - 16384;
        int j = i2 & 7, lane = (i2 >> 3) & 63, kb = (i2 >> 9) & 3, nt = i2 >> 11;
        int k = kb * 32 + (lane >> 4) * 8 + j, n = nt * 16 + (lane & 15);
        Wrpk[i2] = (short)f2bfbits(WrT_f[n * 128 + k]);
    }
}

// ---------- precompute tables ----------
__global__ void k_arel(const float* __restrict__ rela_f, const float* __restrict__ W1_f,
                       float* __restrict__ A_rel, unsigned short* __restrict__ relcat) {
    __shared__ float ld[128];
    int r = blockIdx.x, j = threadIdx.x;
    float rv = rela_f[r * 128 + j];
    ld[j] = rv;
    __syncthreads();
    float acc = 0.f;
    for (int k = 0; k < 128; k++) acc = fmaf(ld[k], W1_f[k * 128 + j], acc);
    A_rel[r * 128 + j] = acc;
    relcat[r * 256 + j] = f2bfbits(acc);
    relcat[r * 256 + 128 + j] = f2bfbits(rv);
}

__global__ void k_atime(const float* __restrict__ pe_f, const float* __restrict__ W1_f,
                        const float* __restrict__ b1_f, float* __restrict__ A_timeb,
                        unsigned short* __restrict__ atimb) {
    __shared__ float ld[32];
    int t = blockIdx.x, j = threadIdx.x;
    if (j < 32) ld[j] = pe_f[t * 32 + j];
    __syncthreads();
    float acc = b1_f[j];
    for (int k = 0; k < 32; k++) acc = fmaf(ld[k], W1_f[(128 + k) * 128 + j], acc);
    A_timeb[t * 128 + j] = acc;
    atimb[t * 128 + j] = f2bfbits(acc);
}

__global__ void k_qws(const float* __restrict__ rela_f, const int* __restrict__ q_rel,
                      const float* __restrict__ bqr_f, const float* __restrict__ WqrT_f,
                      float* __restrict__ Q_ws) {
    alignas(16) __shared__ float qrow[4][128];
    int wv = threadIdx.x >> 6, lane = threadIdx.x & 63;
    int q = blockIdx.x * 4 + wv;
    int qr = q_rel[q];
    const float2* rp = (const float2*)(rela_f + qr * 128);
    float2 rv = rp[lane];
    qrow[wv][2 * lane] = rv.x;
    qrow[wv][2 * lane + 1] = rv.y;
    __syncthreads();
    const float4* wp = (const float4*)(WqrT_f + lane * 128);
    const float4* qp4 = (const float4*)qrow[wv];
    float acc = bqr_f[lane];
    for (int k4 = 0; k4 < 32; k4++) acc = dot4(qp4[k4], wp[k4], acc);
    Q_ws[q * 64 + lane] = acc;
}

// S_b bf16 [50000][64] = hidden[n] . Ws  (full tier only)
__global__ __launch_bounds__(256) void k_snode(const void* __restrict__ hidden,
                        const float* __restrict__ Ws_f,   // [128][64] fp32 (non-transposed)
                        const int* __restrict__ flag, unsigned short* __restrict__ S_b) {
    __shared__ float ws_lds[128][64];                 // 32 KB
    alignas(16) __shared__ float hrow[4][128];
    int tid = threadIdx.x;
    int wv = tid >> 6, lane = tid & 63;
    int f = *flag;
    for (int i = tid; i < 8192; i += 256) ((float*)ws_lds)[i] = Ws_f[i];
    __syncthreads();
    int nb = gridDim.x;
    int q0 = (int)(((long long)blockIdx.x * (N_NODE / 4)) / nb);
    int q1 = (int)(((long long)(blockIdx.x + 1) * (N_NODE / 4)) / nb);
    for (int qg = q0; qg < q1; ++qg) {
        int n = qg * 4 + wv;
        if (f) {
            ushort2 hv = ((const ushort2*)((const bf16*)hidden + (size_t)n * 128))[lane];
            hrow[wv][2 * lane]     = bfbits2f(hv.x);
            hrow[wv][2 * lane + 1] = bfbits2f(hv.y);
        } else {
            float2 hv = ((const float2*)((const float*)hidden + (size_t)n * 128))[lane];
            hrow[wv][2 * lane]     = hv.x;
            hrow[wv][2 * lane + 1] = hv.y;
        }
        // hrow is wave-private: no block barrier needed
        float acc = 0.f;
#pragma unroll 8
        for (int k = 0; k < 128; k++) acc = fmaf(hrow[wv][k], ws_lds[k][lane], acc);
        S_b[(size_t)n * 64 + lane] = f2bfbits(acc);
    }
}

// ---------- SCATTER edge kernel: static spans, MFMA, async hidden DMA, run-merged flush ----------
// No occupancy attribute: natural VGPR ~176 -> 2 blocks/CU. Grid is sized to 512 = 2x256 CU
// so the whole grid is resident (R7 lesson: forcing 3 waves/EU spills to VGPR 84, 1.16 GB FETCH).
// R11 lesson: this exact body is a compiler-schedule local optimum (409us); additive prefetch
// or pre-gather edits regress it 50%+. Do not perturb without inline-asm-level control.
__global__ __launch_bounds__(256) void k_edge_s(
        const int* __restrict__ edges, const int* __restrict__ perm,
        const void* __restrict__ hidden,
        const unsigned short* __restrict__ relcat,   // [r][256] A_rel|rela bf16
        const unsigned short* __restrict__ atimb,    // [t][128] bf16
        const short* __restrict__ W2pk, const short* __restrict__ Wrpk,
        const float* __restrict__ b2_f, const unsigned short* __restrict__ S_b,
        const float* __restrict__ Q_ws, const float* __restrict__ wa_f,
        const int* __restrict__ flag,
        float* __restrict__ up, float* __restrict__ bot) {
    alignas(16) __shared__ short buf[4][16][136];   // wave-private h -> hr buffer
    alignas(16) __shared__ float hid[4][16][128];   // wave-private staged hidden rows (raw)
    int wv = threadIdx.x >> 6, lane = threadIdx.x & 63;
    int c = lane & 15, q = lane >> 4;
    int f = *flag;
    const int ngroups = N_EDGE / 16;  // 50000 exact

    // contiguous span of sorted groups per wave -> runs merge across groups
    int wvid = blockIdx.x * 4 + wv;
    int nw = gridDim.x * 4;
    int g0 = (int)(((long long)wvid * ngroups) / nw);
    int g1 = (int)(((long long)(wvid + 1) * ngroups) / nw);

    short (*bw)[136] = buf[wv];
    float (*hw)[128] = hid[wv];

    int cur_obj = -1;
    float vacc0 = 0.f, vacc1 = 0.f, eacc = 0.f;

    for (int g = g0; g < g1; ++g) {
        int base = g * 16;

        // lane e (<16) holds (perm'd) edge e's packed fields
        int w0 = 0, w1 = 0, w2 = 0;
        if (lane < 16) {
            int ed = perm[base + lane];
            const int* ep = edges + ed * 7;
            w0 = ep[4] | (ep[0] << 16);   // sub | qi<<16   (both < 65536)
            w1 = ep[2] | (ep[6] << 16);   // rel | tim<<16
            w2 = ep[5];                   // obj
        }

        // issue async hidden-row DMA for all 16 edges; consumed in the scatter phase.
        if (f) {
#pragma unroll
            for (int e = 0; e < 16; e++) {
                int sub_e = __shfl(w0, e) & 0xffff;
                const char* src = (const char*)hidden + (size_t)sub_e * 256 + lane * 4;
                gld_lds4(src, &hw[e][0]);               // 256B row (bf16)
            }
        } else {
#pragma unroll
            for (int e = 0; e < 16; e++) {
                int sub_e = __shfl(w0, e) & 0xffff;
                const char* src = (const char*)hidden + (size_t)sub_e * 512 + lane * 4;
                gld_lds4(src,       &hw[e][0]);         // floats 0..63
                gld_lds4(src + 256, &hw[e][64]);        // floats 64..127
            }
        }

        // stage h = lrelu(A_rel + A_timeb) (bf16 coalesced reads) into LDS
#pragma unroll
        for (int e = 0; e < 16; e++) {
            int w1e = __shfl(w1, e);
            int rel_e = w1e & 0xffff, tim_e = w1e >> 16;
            ushort2 a = ((const ushort2*)(relcat + rel_e * 256))[lane];
            ushort2 t = ((const ushort2*)(atimb + tim_e * 128))[lane];
            float h0 = lrelu(bfbits2f(a.x) + bfbits2f(t.x));
            float h1 = lrelu(bfbits2f(a.y) + bfbits2f(t.y));
            *((unsigned int*)&bw[e][2 * lane]) =
                (unsigned)f2bfbits(h0) | ((unsigned)f2bfbits(h1) << 16);
        }

        bf16x8 hf[4];
#pragma unroll
        for (int kb = 0; kb < 4; kb++)
            hf[kb] = *((const bf16x8*)&bw[c][kb * 32 + q * 8]);

        // per-lane row metadata packed (rel=w14&0xffff, sub=w04&0xffff, qi=w04>>16)
        int w04[4], w14[4];
#pragma unroll
        for (int r = 0; r < 4; r++) {
            w14[r] = __shfl(w1, q * 4 + r);
            w04[r] = __shfl(w0, q * 4 + r);
        }

        // hr = lrelu(h@W2 + b2) + rel_e  -> buf (fixup folded into epilogue)
#pragma unroll
        for (int nt = 0; nt < 8; nt++) {
            f32x4 acc = {0.f, 0.f, 0.f, 0.f};
#pragma unroll
            for (int kb = 0; kb < 4; kb++) {
                bf16x8 bfr = *((const bf16x8*)(W2pk + (((nt * 4 + kb) * 64) + lane) * 8));
                acc = __builtin_amdgcn_mfma_f32_16x16x32_bf16(hf[kb], bfr, acc, 0, 0, 0);
            }
            int colg = nt * 16 + c;
            float b2v = b2_f[colg];
#pragma unroll
            for (int r = 0; r < 4; r++) {
                float rv = bfbits2f(relcat[(w14[r] & 0xffff) * 256 + 128 + colg]);
                bw[q * 4 + r][colg] = (short)f2bfbits(lrelu(acc[r] + b2v) + rv);
            }
        }

        // reload fragments (now hr) into the same registers
#pragma unroll
        for (int kb = 0; kb < 4; kb++)
            hf[kb] = *((const bf16x8*)&bw[c][kb * 32 + q * 8]);

        // att = lrelu(S_node + Q_ws + hr@Wr) . w_alpha
        float asum[4] = {0.f, 0.f, 0.f, 0.f};
#pragma unroll
        for (int nt = 0; nt < 4; nt++) {
            f32x4 acc = {0.f, 0.f, 0.f, 0.f};
#pragma unroll
            for (int kb = 0; kb < 4; kb++) {
                bf16x8 bfr = *((const bf16x8*)(Wrpk + (((nt * 4 + kb) * 64) + lane) * 8));
                acc = __builtin_amdgcn_mfma_f32_16x16x32_bf16(hf[kb], bfr, acc, 0, 0, 0);
            }
            int colg = nt * 16 + c;
            float wav = wa_f[colg & 63];
#pragma unroll
            for (int r = 0; r < 4; r++) {
                float av = acc[r] + bfbits2f(S_b[(w04[r] & 0xffff) * 64 + colg])
                         + Q_ws[(w04[r] >> 16) * 64 + colg];
                asum[r] += lrelu(av) * wav;
            }
        }
        float ea[4];
#pragma unroll
        for (int r = 0; r < 4; r++) {
            float a = asum[r];
            a += __shfl_xor(a, 1); a += __shfl_xor(a, 2);
            a += __shfl_xor(a, 4); a += __shfl_xor(a, 8);
            ea[r] = __expf(a);
        }

        // drain the hidden DMA (long since issued), then scatter purely from LDS
        asm volatile("s_waitcnt vmcnt(0)" ::: "memory");
        __builtin_amdgcn_sched_barrier(0);

        // run-merged scatter: edges arrive obj-sorted; flush once per run
#pragma unroll
        for (int e = 0; e < 16; e++) {
            float eav = __shfl(ea[e & 3], (e >> 2) * 16);
            int obj_e = __builtin_amdgcn_readfirstlane(__shfl(w2, e));
            unsigned int pk = *((const unsigned int*)&bw[e][2 * lane]);
            float hr0 = bfbits2f((unsigned short)(pk & 0xffffu));
            float hr1 = bfbits2f((unsigned short)(pk >> 16));
            float hs0, hs1;
            if (f) {
                unsigned int hb = ((const unsigned int*)&hw[e][0])[lane];
                hs0 = bfbits2f((unsigned short)(hb & 0xffffu));
                hs1 = bfbits2f((unsigned short)(hb >> 16));
            } else {
                float2 hv = ((const float2*)&hw[e][0])[lane];
                hs0 = hv.x; hs1 = hv.y;
            }
            float v0 = eav * (hs0 + hr0);
            float v1 = eav * (hs1 + hr1);
            if (obj_e != cur_obj) {
                if (cur_obj >= 0) {
                    float* dst = up + cur_obj * 128 + 2 * lane;
                    unsafeAtomicAdd(dst,     vacc0);
                    unsafeAtomicAdd(dst + 1, vacc1);
                    if (lane == 0) unsafeAtomicAdd(bot + cur_obj, eacc);
                }
                cur_obj = obj_e;
                vacc0 = v0; vacc1 = v1; eacc = eav;
            } else {
                vacc0 += v0; vacc1 += v1; eacc += eav;
            }
        }
    }
    // final flush of the span's trailing run
    if (cur_obj >= 0) {
        float* dst = up + cur_obj * 128 + 2 * lane;
        unsafeAtomicAdd(dst,     vacc0);
        unsafeAtomicAdd(dst + 1, vacc1);
        if (lane == 0) unsafeAtomicAdd(bot + cur_obj, eacc);
    }
}

// ---------- COMPACT-tier fallback (atomics into d_out) ----------
__global__ __launch_bounds__(256) void k_edge_c(
        const int* __restrict__ edges, const void* __restrict__ hidden,
        const float* __restrict__ rela_f,
        const float* __restrict__ A_rel, const float* __restrict__ A_timeb,
        const float* __restrict__ W2T, const float* __restrict__ WrT,
        const float* __restrict__ WsT, const float* __restrict__ b2_f,
        const float* __restrict__ Q_ws, const float* __restrict__ wa_f,
        const int* __restrict__ flag,
        float* __restrict__ bot, void* __restrict__ dout) {
    alignas(16) __shared__ float lds_h[4][EPW][128];
    alignas(16) __shared__ float lds_hr[4][EPW][128];
    alignas(16) __shared__ float lds_hs[4][EPW][128];
    int wv = threadIdx.x >> 6, lane = threadIdx.x & 63;
    int f = *flag;
    int nwaves = gridDim.x * 4;
    const int ngroups = N_EDGE / EPW;
    float b20 = b2_f[2 * lane], b21 = b2_f[2 * lane + 1];
    float wa = wa_f[lane];
    for (int g = blockIdx.x * 4 + wv; g < ngroups; g += nwaves) {
        int base = g * EPW;
        int rel[EPW], sub[EPW], obj[EPW], qi[EPW], tim[EPW];
#pragma unroll
        for (int e = 0; e < EPW; e++) {
            const int* ep = edges + (base + e) * 7;
            qi[e] = ep[0]; rel[e] = ep[2]; sub[e] = ep[4];
            obj[e] = ep[5]; tim[e] = ep[6];
        }
        float hs0[EPW], hs1[EPW];
#pragma unroll
        for (int e = 0; e < EPW; e++) {
            const float2* ar = (const float2*)(A_rel + rel[e] * 128);
            const float2* at = (const float2*)(A_timeb + tim[e] * 128);
            float2 a = ar[lane], t = at[lane];
            lds_h[wv][e][2 * lane]     = lrelu(a.x + t.x);
            lds_h[wv][e][2 * lane + 1] = lrelu(a.y + t.y);
            if (f) {
                ushort2 hv = ((const ushort2*)((const bf16*)hidden + sub[e] * 128))[lane];
                hs0[e] = bfbits2f(hv.x); hs1[e] = bfbits2f(hv.y);
            } else {
                float2 hv = ((const float2*)((const float*)hidden + sub[e] * 128))[lane];
                hs0[e] = hv.x; hs1[e] = hv.y;
            }
            lds_hs[wv][e][2 * lane]     = hs0[e];
            lds_hs[wv][e][2 * lane + 1] = hs1[e];
        }
        float acc0[EPW], acc1[EPW];
#pragma unroll
        for (int e = 0; e < EPW; e++) { acc0[e] = b20; acc1[e] = b21; }
        const float4* w0p = (const float4*)(W2T + (2 * lane) * 128);
        const float4* w1p = (const float4*)(W2T + (2 * lane + 1) * 128);
        for (int k4 = 0; k4 < 32; k4++) {
            float4 w0 = w0p[k4], w1 = w1p[k4];
#pragma unroll
            for (int e = 0; e < EPW; e++) {
                float4 h = ((const float4*)lds_h[wv][e])[k4];
                acc0[e] = dot4(h, w0, acc0[e]);
                acc1[e] = dot4(h, w1, acc1[e]);
            }
        }
        float hr0[EPW], hr1[EPW];
#pragma unroll
        for (int e = 0; e < EPW; e++) {
            const float2* rp = (const float2*)(rela_f + rel[e] * 128);
            float2 rv = rp[lane];
            hr0[e] = lrelu(acc0[e]) + rv.x;
            hr1[e] = lrelu(acc1[e]) + rv.y;
            lds_hr[wv][e][2 * lane]     = hr0[e];
            lds_hr[wv][e][2 * lane + 1] = hr1[e];
        }
        float att[EPW];
#pragma unroll
        for (int e = 0; e < EPW; e++) att[e] = Q_ws[qi[e] * 64 + lane];
        const float4* wrp = (const float4*)(WrT + lane * 128);
        const float4* wsp = (const float4*)(WsT + lane * 128);
        for (int k4 = 0; k4 < 32; k4++) {
            float4 w = wrp[k4], w2 = wsp[k4];
#pragma unroll
            for (int e = 0; e < EPW; e++) {
                float4 hr4 = ((const float4*)lds_hr[wv][e])[k4];
                float4 hs4 = ((const float4*)lds_hs[wv][e])[k4];
                att[e] = dot4(hr4, w, att[e]);
                att[e] = dot4(hs4, w2, att[e]);
            }
        }
        float ea[EPW];
#pragma unroll
        for (int e = 0; e < EPW; e++) {
            float a = lrelu(att[e]) * wa;
            a += __shfl_xor(a, 32); a += __shfl_xor(a, 16); a += __shfl_xor(a, 8);
            a += __shfl_xor(a, 4);  a += __shfl_xor(a, 2);  a += __shfl_xor(a, 1);
            ea[e] = __expf(a);
        }
#pragma unroll
        for (int e = 0; e < EPW; e++) {
            float v0 = ea[e] * (hs0[e] + hr0[e]);
            float v1 = ea[e] * (hs1[e] + hr1[e]);
            if (!f) {
                float* dst = (float*)dout + obj[e] * 128 + 2 * lane;
                unsafeAtomicAdd(dst,     v0);
                unsafeAtomicAdd(dst + 1, v1);
            } else {
                atom_pk_bf16((unsigned int*)dout + obj[e] * 64 + lane, v0, v1);
            }
            if (lane == 0) unsafeAtomicAdd(bot + obj[e], ea[e]);
        }
    }
}

// ---------- epilogue: out[n] = (up[n]/bot[n]) @ Wh; Wh cached in LDS, block loops nodes ----------
__global__ __launch_bounds__(256) void k_out(const float* __restrict__ up,
                      const float* __restrict__ bot,
                      const float* __restrict__ Wh_f, void* __restrict__ dout,
                      const int* __restrict__ flag, int tier_full) {
    __shared__ float wh[124][128];   // 63.5 KB: rows 0..123 cached; 124..127 from L2
    __shared__ float m[2][128];
    int tid = threadIdx.x;
    int half = tid >> 7, j = tid & 127;
    int f = *flag;
    for (int i = tid; i < 124 * 128; i += 256) ((float*)wh)[i] = Wh_f[i];
    __syncthreads();
    int nb = gridDim.x;
    int p0 = (int)(((long long)blockIdx.x * (N_NODE / 2)) / nb);
    int p1 = (int)(((long long)(blockIdx.x + 1) * (N_NODE / 2)) / nb);
    for (int p = p0; p < p1; ++p) {
        int n = p * 2 + half;
        float inv = 1.f / (bot[n] + 1e-5f);
        float num;
        if (tier_full) {
            num = up[(size_t)n * 128 + j];
        } else if (!f) {
            num = ((const float*)dout)[(size_t)n * 128 + j];
        } else {
            unsigned int w = ((const unsigned int*)dout)[(size_t)n * 64 + (j >> 1)];
            num = bfbits2f((unsigned short)((j & 1) ? (w >> 16) : (w & 0xffffu)));
        }
        m[half][j] = num * inv;
        __syncthreads();
        float acc = 0.f;
#pragma unroll 4
        for (int k = 0; k < 124; k++) acc = fmaf(m[half][k], wh[k][j], acc);
#pragma unroll
        for (int k = 124; k < 128; k++) acc = fmaf(m[half][k], Wh_f[k * 128 + j], acc);
        if (f) ((bf16*)dout)[(size_t)n * 128 + j] = __float2bfloat16(acc);
        else   ((float*)dout)[(size_t)n * 128 + j] = acc;
        __syncthreads();   // protect m before next iteration overwrites it
    }
}

// ---------- launcher ----------
extern "C" void kernel_launch(void* const* d_in, const int* in_sizes, int n_in,
                              void* d_out, int out_size, void* d_ws, size_t ws_size,
                              hipStream_t stream) {
    const void* hidden = d_in[0];
    const void* rela   = d_in[1];
    const void* pe     = d_in[2];
    const void* W1     = d_in[3];
    const void* b1     = d_in[4];
    const void* W2     = d_in[5];
    const void* b2     = d_in[6];
    const void* Ws     = d_in[7];
    const void* Wr     = d_in[8];
    const void* Wqr    = d_in[9];
    const void* bqr    = d_in[10];
    const void* walpha = d_in[11];
    const void* Wh     = d_in[12];
    const int* q_rel   = (const int*)d_in[13];
    const int* edges   = (const int*)d_in[14];

    float* ws = (float*)d_ws;
    size_t off = 0;
    int*   flag    = (int*)(ws + off); off += 4;
    float* pool    = ws + off;
    float* rela_f  = pool;
    float* pe_f    = rela_f + SEG_RELA;
    float* W1_f    = pe_f + SEG_PE;
    float* b1_f    = W1_f + SEG_W1;
    float* W2T_f   = b1_f + SEG_B1;
    float* b2_f    = W2T_f + SEG_W2T;
    float* WsT_f   = b2_f + SEG_B2;
    float* Ws_f    = WsT_f + SEG_WST;
    float* WrT_f   = Ws_f + SEG_WS;
    float* WqrT_f  = WrT_f + SEG_WRT;
    float* bqr_f   = WqrT_f + SEG_WQRT;
    float* wa_f    = bqr_f + SEG_BQR;
    float* Wh_f    = wa_f + SEG_WA;
    off += POOL_TOTAL;
    float* A_rel   = ws + off; off += 401 * 128;
    float* A_timeb = ws + off; off += 1000 * 128;
    float* Q_ws    = ws + off; off += N_QUERY * 64;
    float* bot     = ws + off; off += N_NODE;
    short* W2pk    = (short*)(ws + off); off += 8192;
    short* Wrpk    = (short*)(ws + off); off += 4096;
    unsigned short* relcat = (unsigned short*)(ws + off); off += 401 * 128;   // 401*256 bf16
    unsigned short* atimb  = (unsigned short*)(ws + off); off += 1000 * 64;   // 1000*128 bf16
    unsigned short* S_b    = (unsigned short*)(ws + off); off += (size_t)N_NODE * 32; // 50000*64 bf16
    float* up      = ws + off; off += (size_t)N_NODE * 128;
    int*   perm    = (int*)(ws + off); off += N_EDGE;
    int*   cnt     = (int*)(ws + off); off += N_NODE + 32;
    int*   cur     = (int*)(ws + off); off += N_NODE + 32;
    int*   tot     = (int*)(ws + off); off += 64;
    size_t full_floats = off;   // ~9.46M floats = 37.85 MB (proven ws >= 39.6 MB)

    int tier_full = (ws_size >= full_floats * sizeof(float)) ? 1 : 0;

    if (tier_full) {
        // DMA memset nodes: flag-independent, cheaper than a zeroing kernel
        hipMemsetAsync(bot, 0, (size_t)N_NODE * sizeof(float), stream);
        hipMemsetAsync(up,  0, (size_t)N_NODE * 128 * sizeof(float), stream);
        hipMemsetAsync(cnt, 0, (size_t)(N_NODE + 32) * sizeof(int), stream);
    }

    k_detect<<<1, 1, 0, stream>>>((const unsigned int*)pe, flag);
    if (!tier_full) {
        k_zero<<<2048, 256, 0, stream>>>((unsigned int*)d_out, out_size, flag, bot, up, cnt, 0);
    }
    k_convert<<<(POOL_TOTAL + 255) / 256, 256, 0, stream>>>(
        rela, pe, W1, b1, W2, b2, Ws, Wr, Wqr, bqr, walpha, Wh, flag, pool);
    k_arel<<<401, 128, 0, stream>>>(rela_f, W1_f, A_rel, relcat);
    k_atime<<<1000, 128, 0, stream>>>(pe_f, W1_f, b1_f, A_timeb, atimb);
    k_qws<<<N_QUERY / 4, 256, 0, stream>>>(rela_f, q_rel, bqr_f, WqrT_f, Q_ws);

    if (tier_full) {
        k_pack<<<96, 256, 0, stream>>>(W2T_f, WrT_f, W2pk, Wrpk);
        k_snode<<<1024, 256, 0, stream>>>(hidden, Ws_f, flag, S_b);
        k_hist<<<1024, 256, 0, stream>>>(edges, cnt);
        k_scan1<<<49, 1024, 0, stream>>>(cnt, cur, tot);
        k_scan2<<<49, 1024, 0, stream>>>(tot, cur);
        k_scat<<<1024, 256, 0, stream>>>(edges, cur, perm);
        // 512 blocks = 2 blocks/CU x 256 CU at VGPR=176: whole grid resident in one batch
        k_edge_s<<<512, 256, 0, stream>>>(edges, perm, hidden, relcat, atimb, W2pk, Wrpk,
                                          b2_f, S_b, Q_ws, wa_f, flag, up, bot);
    } else {
        k_edge_c<<<1536, 256, 0, stream>>>(edges, hidden, rela_f, A_rel, A_timeb,
                                           W2T_f, WrT_f, WsT_f, b2_f, Q_ws, wa_f,
                                           flag, bot, d_out);
    }

    k_out<<<500, 256, 0, stream>>>(up, bot, Wh_f, d_out, flag, tier_full);
}

// Round 14
// 760.617 us; speedup vs baseline: 1.4848x; 1.0061x over previous
//
#include <hip/hip_runtime.h>
#include <hip/hip_bf16.h>

typedef __hip_bfloat16 bf16;
typedef __attribute__((ext_vector_type(8))) short bf16x8;
typedef __attribute__((ext_vector_type(4))) float f32x4;

#define N_NODE   50000
#define N_EDGE   800000
#define N_QUERY  512
#define EPW      8

__device__ __forceinline__ float bfbits2f(unsigned short u) {
    return __uint_as_float(((unsigned)u) << 16);
}
__device__ __forceinline__ unsigned short f2bfbits(float f) {
    unsigned int u = __float_as_uint(f);
    return (unsigned short)((u + 0x7fffu + ((u >> 16) & 1u)) >> 16);  // RNE
}
__device__ __forceinline__ float lrelu(float x) { return x > 0.f ? x : 0.01f * x; }
__device__ __forceinline__ float dot4(float4 a, float4 b, float acc) {
    acc = fmaf(a.x, b.x, acc); acc = fmaf(a.y, b.y, acc);
    acc = fmaf(a.z, b.z, acc); acc = fmaf(a.w, b.w, acc);
    return acc;
}
// async global->LDS DMA: per-lane 4B from per-lane global addr into (base + lane*4)
__device__ __forceinline__ void gld_lds4(const void* g, void* l) {
    __builtin_amdgcn_global_load_lds(
        (const __attribute__((address_space(1))) void*)g,
        (__attribute__((address_space(3))) void*)l, 4, 0, 0);
}
__device__ __forceinline__ void atom_pk_bf16(unsigned int* addr, float a0, float a1) {
    unsigned int old = *((volatile unsigned int*)addr);
    while (true) {
        float f0 = bfbits2f((unsigned short)(old & 0xffffu)) + a0;
        float f1 = bfbits2f((unsigned short)(old >> 16)) + a1;
        unsigned int nv = (unsigned int)f2bfbits(f0) | ((unsigned int)f2bfbits(f1) << 16);
        unsigned int prev = atomicCAS(addr, old, nv);
        if (prev == old) break;
        old = prev;
    }
}

// ---------- dtype detection (pe[0] word: fp32 -> 0x00000000, bf16 -> 0x3F800000) ----------
__global__ void k_detect(const unsigned int* __restrict__ pe_raw, int* __restrict__ flag) {
    *flag = (pe_raw[0] != 0u) ? 1 : 0;   // 1 = bf16 inputs, 0 = fp32 inputs
}

// ---------- zero accumulators (compact-tier fallback only; full tier uses memset nodes) ----------
__global__ void k_zero(unsigned int* __restrict__ out_w, int out_elems,
                       const int* __restrict__ flag,
                       float* __restrict__ bot, float* __restrict__ up,
                       int* __restrict__ cnt, int tier_full) {
    int f = *flag;
    int stride = gridDim.x * blockDim.x;
    int tid = blockIdx.x * blockDim.x + threadIdx.x;
    for (int i = tid; i < N_NODE; i += stride) bot[i] = 0.f;
    if (tier_full) {
        for (int i = tid; i < N_NODE * 128; i += stride) up[i] = 0.f;
        for (int i = tid; i < N_NODE + 32; i += stride) cnt[i] = 0;
    } else {
        int out_words = f ? (out_elems >> 1) : out_elems;
        for (int i = tid; i < out_words; i += stride) out_w[i] = 0u;
    }
}

// ---------- counting sort of edges by obj: hist -> parallel scan -> scatter ----------
__global__ void k_hist(const int* __restrict__ edges, int* __restrict__ cnt) {
    int stride = gridDim.x * blockDim.x;
    for (int i = blockIdx.x * blockDim.x + threadIdx.x; i < N_EDGE; i += stride)
        atomicAdd(&cnt[edges[i * 7 + 5]], 1);
}

// parallel scan phase 1: 49 blocks x 1024; coalesced load, in-LDS inclusive scan,
// write block-local EXCLUSIVE prefix to cur, block total to tot[b].
__global__ __launch_bounds__(1024) void k_scan1(const int* __restrict__ cnt,
                                                int* __restrict__ cur,
                                                int* __restrict__ tot) {
    __shared__ int part[1024];
    int t = threadIdx.x;
    int idx = blockIdx.x * 1024 + t;
    int v = (idx < N_NODE) ? cnt[idx] : 0;
    part[t] = v;
    __syncthreads();
    for (int d = 1; d < 1024; d <<= 1) {
        int tmp = (t >= d) ? part[t - d] : 0;
        __syncthreads();
        part[t] += tmp;
        __syncthreads();
    }
    if (idx < N_NODE) cur[idx] = part[t] - v;     // exclusive, block-local
    if (t == 1023) tot[blockIdx.x] = part[1023];
}

// parallel scan phase 2: 49 blocks x 1024; add global offset sum(tot[0..b)).
__global__ __launch_bounds__(1024) void k_scan2(const int* __restrict__ tot,
                                                int* __restrict__ cur) {
    __shared__ int offs;
    if (threadIdx.x == 0) {
        int s = 0;
        for (int i = 0; i < (int)blockIdx.x; i++) s += tot[i];
        offs = s;
    }
    __syncthreads();
    int idx = blockIdx.x * 1024 + threadIdx.x;
    if (idx < N_NODE) cur[idx] += offs;
}

__global__ void k_scat(const int* __restrict__ edges, int* __restrict__ cur,
                       int* __restrict__ perm) {
    int stride = gridDim.x * blockDim.x;
    for (int i = blockIdx.x * blockDim.x + threadIdx.x; i < N_EDGE; i += stride) {
        int obj = edges[i * 7 + 5];
        int pos = atomicAdd(&cur[obj], 1);
        perm[pos] = i;
    }
}

// ---------- convert all small tensors to fp32 pool (transposes W2/Ws/Wr/Wqr) ----------
#define SEG_RELA   51328
#define SEG_PE     32000
#define SEG_W1     20480
#define SEG_B1     128
#define SEG_W2T    16384
#define SEG_B2     128
#define SEG_WST    8192
#define SEG_WS     8192
#define SEG_WRT    8192
#define SEG_WQRT   8192
#define SEG_BQR    64
#define SEG_WA     64
#define SEG_WH     16384
#define POOL_TOTAL (SEG_RELA+SEG_PE+SEG_W1+SEG_B1+SEG_W2T+SEG_B2+SEG_WST+SEG_WS+SEG_WRT+SEG_WQRT+SEG_BQR+SEG_WA+SEG_WH)

__global__ void k_convert(const void* rela, const void* pe, const void* W1, const void* b1,
                          const void* W2, const void* b2, const void* Ws, const void* Wr,
                          const void* Wqr, const void* bqr, const void* walpha, const void* Wh,
                          const int* __restrict__ flag, float* __restrict__ pool) {
    int idx = blockIdx.x * blockDim.x + threadIdx.x;
    int f = *flag;
    auto ld = [&](const void* p, int i) -> float {
        return f ? __bfloat162float(((const bf16*)p)[i]) : ((const float*)p)[i];
    };
    int i = idx;
    if (i < SEG_RELA) { pool[idx] = ld(rela, i); return; } i -= SEG_RELA;
    if (i < SEG_PE)   { pool[idx] = ld(pe, i); return; }   i -= SEG_PE;
    if (i < SEG_W1)   { pool[idx] = ld(W1, i); return; }   i -= SEG_W1;
    if (i < SEG_B1)   { pool[idx] = ld(b1, i); return; }   i -= SEG_B1;
    if (i < SEG_W2T)  { pool[idx] = ld(W2, (i & 127) * 128 + (i >> 7)); return; } i -= SEG_W2T;
    if (i < SEG_B2)   { pool[idx] = ld(b2, i); return; }   i -= SEG_B2;
    if (i < SEG_WST)  { pool[idx] = ld(Ws,  (i & 127) * 64 + (i >> 7)); return; } i -= SEG_WST;
    if (i < SEG_WS)   { pool[idx] = ld(Ws, i); return; }   i -= SEG_WS;
    if (i < SEG_WRT)  { pool[idx] = ld(Wr,  (i & 127) * 64 + (i >> 7)); return; } i -= SEG_WRT;
    if (i < SEG_WQRT) { pool[idx] = ld(Wqr, (i & 127) * 64 + (i >> 7)); return; } i -= SEG_WQRT;
    if (i < SEG_BQR)  { pool[idx] = ld(bqr, i); return; }  i -= SEG_BQR;
    if (i < SEG_WA)   { pool[idx] = ld(walpha, i); return; } i -= SEG_WA;
    if (i < SEG_WH)   { pool[idx] = ld(Wh, i); return; }
}

// ---------- pack W2/Wr into MFMA B-fragment order (bf16) ----------
__global__ void k_pack(const float* __restrict__ W2T_f, const float* __restrict__ WrT_f,
                       short* __restrict__ W2pk, short* __restrict__ Wrpk) {
    int idx = blockIdx.x * blockDim.x + threadIdx.x;
    if (idx < 16384) {
        int j = idx & 7, lane = (idx >> 3) & 63, kb = (idx >> 9) & 3, nt = idx >> 11;
        int k = kb * 32 + (lane >> 4) * 8 + j, n = nt * 16 + (lane & 15);
        W2pk[idx] = (short)f2bfbits(W2T_f[n * 128 + k]);
    } else if (idx < 16384 + 8192) {
        int i2 = idx - 16384;
        int j = i2 & 7, lane = (i2 >> 3) & 63, kb = (i2 >> 9) & 3, nt = i2 >> 11;
        int k = kb * 32 + (lane >> 4) * 8 + j, n = nt * 16 + (lane & 15);
        Wrpk[i2] = (short)f2bfbits(WrT_f[n * 128 + k]);
    }
}

// ---------- precompute tables ----------
__global__ void k_arel(const float* __restrict__ rela_f, const float* __restrict__ W1_f,
                       float* __restrict__ A_rel, unsigned short* __restrict__ relcat) {
    __shared__ float ld[128];
    int r = blockIdx.x, j = threadIdx.x;
    float rv = rela_f[r * 128 + j];
    ld[j] = rv;
    __syncthreads();
    float acc = 0.f;
    for (int k = 0; k < 128; k++) acc = fmaf(ld[k], W1_f[k * 128 + j], acc);
    A_rel[r * 128 + j] = acc;
    relcat[r * 256 + j] = f2bfbits(acc);
    relcat[r * 256 + 128 + j] = f2bfbits(rv);
}

__global__ void k_atime(const float* __restrict__ pe_f, const float* __restrict__ W1_f,
                        const float* __restrict__ b1_f, float* __restrict__ A_timeb,
                        unsigned short* __restrict__ atimb) {
    __shared__ float ld[32];
    int t = blockIdx.x, j = threadIdx.x;
    if (j < 32) ld[j] = pe_f[t * 32 + j];
    __syncthreads();
    float acc = b1_f[j];
    for (int k = 0; k < 32; k++) acc = fmaf(ld[k], W1_f[(128 + k) * 128 + j], acc);
    A_timeb[t * 128 + j] = acc;
    atimb[t * 128 + j] = f2bfbits(acc);
}

__global__ void k_qws(const float* __restrict__ rela_f, const int* __restrict__ q_rel,
                      const float* __restrict__ bqr_f, const float* __restrict__ WqrT_f,
                      float* __restrict__ Q_ws) {
    alignas(16) __shared__ float qrow[4][128];
    int wv = threadIdx.x >> 6, lane = threadIdx.x & 63;
    int q = blockIdx.x * 4 + wv;
    int qr = q_rel[q];
    const float2* rp = (const float2*)(rela_f + qr * 128);
    float2 rv = rp[lane];
    qrow[wv][2 * lane] = rv.x;
    qrow[wv][2 * lane + 1] = rv.y;
    __syncthreads();
    const float4* wp = (const float4*)(WqrT_f + lane * 128);
    const float4* qp4 = (const float4*)qrow[wv];
    float acc = bqr_f[lane];
    for (int k4 = 0; k4 < 32; k4++) acc = dot4(qp4[k4], wp[k4], acc);
    Q_ws[q * 64 + lane] = acc;
}

// S_b bf16 [50000][64] = hidden[n] . Ws  (full tier only)
__global__ __launch_bounds__(256) void k_snode(const void* __restrict__ hidden,
                        const float* __restrict__ Ws_f,   // [128][64] fp32 (non-transposed)
                        const int* __restrict__ flag, unsigned short* __restrict__ S_b) {
    __shared__ float ws_lds[128][64];                 // 32 KB
    alignas(16) __shared__ float hrow[4][128];
    int tid = threadIdx.x;
    int wv = tid >> 6, lane = tid & 63;
    int f = *flag;
    for (int i = tid; i < 8192; i += 256) ((float*)ws_lds)[i] = Ws_f[i];
    __syncthreads();
    int nb = gridDim.x;
    int q0 = (int)(((long long)blockIdx.x * (N_NODE / 4)) / nb);
    int q1 = (int)(((long long)(blockIdx.x + 1) * (N_NODE / 4)) / nb);
    for (int qg = q0; qg < q1; ++qg) {
        int n = qg * 4 + wv;
        if (f) {
            ushort2 hv = ((const ushort2*)((const bf16*)hidden + (size_t)n * 128))[lane];
            hrow[wv][2 * lane]     = bfbits2f(hv.x);
            hrow[wv][2 * lane + 1] = bfbits2f(hv.y);
        } else {
            float2 hv = ((const float2*)((const float*)hidden + (size_t)n * 128))[lane];
            hrow[wv][2 * lane]     = hv.x;
            hrow[wv][2 * lane + 1] = hv.y;
        }
        // hrow is wave-private: no block barrier needed
        float acc = 0.f;
#pragma unroll 8
        for (int k = 0; k < 128; k++) acc = fmaf(hrow[wv][k], ws_lds[k][lane], acc);
        S_b[(size_t)n * 64 + lane] = f2bfbits(acc);
    }
}

// ---------- SCATTER edge kernel: static spans, MFMA, async hidden DMA, run-merged flush ----------
// No occupancy attribute: natural VGPR ~176 -> 2 blocks/CU. Grid is sized to 512 = 2x256 CU
// so the whole grid is resident (R7 lesson: forcing 3 waves/EU spills to VGPR 84, 1.16 GB FETCH).
// R11 lesson: this exact body is a compiler-schedule local optimum (409us); additive prefetch
// or pre-gather edits regress it 50%+. Do not perturb without inline-asm-level control.
__global__ __launch_bounds__(256) void k_edge_s(
        const int* __restrict__ edges, const int* __restrict__ perm,
        const void* __restrict__ hidden,
        const unsigned short* __restrict__ relcat,   // [r][256] A_rel|rela bf16
        const unsigned short* __restrict__ atimb,    // [t][128] bf16
        const short* __restrict__ W2pk, const short* __restrict__ Wrpk,
        const float* __restrict__ b2_f, const unsigned short* __restrict__ S_b,
        const float* __restrict__ Q_ws, const float* __restrict__ wa_f,
        const int* __restrict__ flag,
        float* __restrict__ up, float* __restrict__ bot) {
    alignas(16) __shared__ short buf[4][16][136];   // wave-private h -> hr buffer
    alignas(16) __shared__ float hid[4][16][128];   // wave-private staged hidden rows (raw)
    int wv = threadIdx.x >> 6, lane = threadIdx.x & 63;
    int c = lane & 15, q = lane >> 4;
    int f = *flag;
    const int ngroups = N_EDGE / 16;  // 50000 exact

    // contiguous span of sorted groups per wave -> runs merge across groups
    int wvid = blockIdx.x * 4 + wv;
    int nw = gridDim.x * 4;
    int g0 = (int)(((long long)wvid * ngroups) / nw);
    int g1 = (int)(((long long)(wvid + 1) * ngroups) / nw);

    short (*bw)[136] = buf[wv];
    float (*hw)[128] = hid[wv];

    int cur_obj = -1;
    float vacc0 = 0.f, vacc1 = 0.f, eacc = 0.f;

    for (int g = g0; g < g1; ++g) {
        int base = g * 16;

        // lane e (<16) holds (perm'd) edge e's packed fields
        int w0 = 0, w1 = 0, w2 = 0;
        if (lane < 16) {
            int ed = perm[base + lane];
            const int* ep = edges + ed * 7;
            w0 = ep[4] | (ep[0] << 16);   // sub | qi<<16   (both < 65536)
            w1 = ep[2] | (ep[6] << 16);   // rel | tim<<16
            w2 = ep[5];                   // obj
        }

        // issue async hidden-row DMA for all 16 edges; consumed in the scatter phase.
        if (f) {
#pragma unroll
            for (int e = 0; e < 16; e++) {
                int sub_e = __shfl(w0, e) & 0xffff;
                const char* src = (const char*)hidden + (size_t)sub_e * 256 + lane * 4;
                gld_lds4(src, &hw[e][0]);               // 256B row (bf16)
            }
        } else {
#pragma unroll
            for (int e = 0; e < 16; e++) {
                int sub_e = __shfl(w0, e) & 0xffff;
                const char* src = (const char*)hidden + (size_t)sub_e * 512 + lane * 4;
                gld_lds4(src,       &hw[e][0]);         // floats 0..63
                gld_lds4(src + 256, &hw[e][64]);        // floats 64..127
            }
        }

        // stage h = lrelu(A_rel + A_timeb) (bf16 coalesced reads) into LDS
#pragma unroll
        for (int e = 0; e < 16; e++) {
            int w1e = __shfl(w1, e);
            int rel_e = w1e & 0xffff, tim_e = w1e >> 16;
            ushort2 a = ((const ushort2*)(relcat + rel_e * 256))[lane];
            ushort2 t = ((const ushort2*)(atimb + tim_e * 128))[lane];
            float h0 = lrelu(bfbits2f(a.x) + bfbits2f(t.x));
            float h1 = lrelu(bfbits2f(a.y) + bfbits2f(t.y));
            *((unsigned int*)&bw[e][2 * lane]) =
                (unsigned)f2bfbits(h0) | ((unsigned)f2bfbits(h1) << 16);
        }

        bf16x8 hf[4];
#pragma unroll
        for (int kb = 0; kb < 4; kb++)
            hf[kb] = *((const bf16x8*)&bw[c][kb * 32 + q * 8]);

        // per-lane row metadata packed (rel=w14&0xffff, sub=w04&0xffff, qi=w04>>16)
        int w04[4], w14[4];
#pragma unroll
        for (int r = 0; r < 4; r++) {
            w14[r] = __shfl(w1, q * 4 + r);
            w04[r] = __shfl(w0, q * 4 + r);
        }

        // hr = lrelu(h@W2 + b2) + rel_e  -> buf (fixup folded into epilogue)
#pragma unroll
        for (int nt = 0; nt < 8; nt++) {
            f32x4 acc = {0.f, 0.f, 0.f, 0.f};
#pragma unroll
            for (int kb = 0; kb < 4; kb++) {
                bf16x8 bfr = *((const bf16x8*)(W2pk + (((nt * 4 + kb) * 64) + lane) * 8));
                acc = __builtin_amdgcn_mfma_f32_16x16x32_bf16(hf[kb], bfr, acc, 0, 0, 0);
            }
            int colg = nt * 16 + c;
            float b2v = b2_f[colg];
#pragma unroll
            for (int r = 0; r < 4; r++) {
                float rv = bfbits2f(relcat[(w14[r] & 0xffff) * 256 + 128 + colg]);
                bw[q * 4 + r][colg] = (short)f2bfbits(lrelu(acc[r] + b2v) + rv);
            }
        }

        // reload fragments (now hr) into the same registers
#pragma unroll
        for (int kb = 0; kb < 4; kb++)
            hf[kb] = *((const bf16x8*)&bw[c][kb * 32 + q * 8]);

        // att = lrelu(S_node + Q_ws + hr@Wr) . w_alpha
        float asum[4] = {0.f, 0.f, 0.f, 0.f};
#pragma unroll
        for (int nt = 0; nt < 4; nt++) {
            f32x4 acc = {0.f, 0.f, 0.f, 0.f};
#pragma unroll
            for (int kb = 0; kb < 4; kb++) {
                bf16x8 bfr = *((const bf16x8*)(Wrpk + (((nt * 4 + kb) * 64) + lane) * 8));
                acc = __builtin_amdgcn_mfma_f32_16x16x32_bf16(hf[kb], bfr, acc, 0, 0, 0);
            }
            int colg = nt * 16 + c;
            float wav = wa_f[colg & 63];
#pragma unroll
            for (int r = 0; r < 4; r++) {
                float av = acc[r] + bfbits2f(S_b[(w04[r] & 0xffff) * 64 + colg])
                         + Q_ws[(w04[r] >> 16) * 64 + colg];
                asum[r] += lrelu(av) * wav;
            }
        }
        float ea[4];
#pragma unroll
        for (int r = 0; r < 4; r++) {
            float a = asum[r];
            a += __shfl_xor(a, 1); a += __shfl_xor(a, 2);
            a += __shfl_xor(a, 4); a += __shfl_xor(a, 8);
            ea[r] = __expf(a);
        }

        // drain the hidden DMA (long since issued), then scatter purely from LDS
        asm volatile("s_waitcnt vmcnt(0)" ::: "memory");
        __builtin_amdgcn_sched_barrier(0);

        // run-merged scatter: edges arrive obj-sorted; flush once per run
#pragma unroll
        for (int e = 0; e < 16; e++) {
            float eav = __shfl(ea[e & 3], (e >> 2) * 16);
            int obj_e = __builtin_amdgcn_readfirstlane(__shfl(w2, e));
            unsigned int pk = *((const unsigned int*)&bw[e][2 * lane]);
            float hr0 = bfbits2f((unsigned short)(pk & 0xffffu));
            float hr1 = bfbits2f((unsigned short)(pk >> 16));
            float hs0, hs1;
            if (f) {
                unsigned int hb = ((const unsigned int*)&hw[e][0])[lane];
                hs0 = bfbits2f((unsigned short)(hb & 0xffffu));
                hs1 = bfbits2f((unsigned short)(hb >> 16));
            } else {
                float2 hv = ((const float2*)&hw[e][0])[lane];
                hs0 = hv.x; hs1 = hv.y;
            }
            float v0 = eav * (hs0 + hr0);
            float v1 = eav * (hs1 + hr1);
            if (obj_e != cur_obj) {
                if (cur_obj >= 0) {
                    float* dst = up + cur_obj * 128 + 2 * lane;
                    unsafeAtomicAdd(dst,     vacc0);
                    unsafeAtomicAdd(dst + 1, vacc1);
                    if (lane == 0) unsafeAtomicAdd(bot + cur_obj, eacc);
                }
                cur_obj = obj_e;
                vacc0 = v0; vacc1 = v1; eacc = eav;
            } else {
                vacc0 += v0; vacc1 += v1; eacc += eav;
            }
        }
    }
    // final flush of the span's trailing run
    if (cur_obj >= 0) {
        float* dst = up + cur_obj * 128 + 2 * lane;
        unsafeAtomicAdd(dst,     vacc0);
        unsafeAtomicAdd(dst + 1, vacc1);
        if (lane == 0) unsafeAtomicAdd(bot + cur_obj, eacc);
    }
}

// ---------- COMPACT-tier fallback (atomics into d_out) ----------
__global__ __launch_bounds__(256) void k_edge_c(
        const int* __restrict__ edges, const void* __restrict__ hidden,
        const float* __restrict__ rela_f,
        const float* __restrict__ A_rel, const float* __restrict__ A_timeb,
        const float* __restrict__ W2T, const float* __restrict__ WrT,
        const float* __restrict__ WsT, const float* __restrict__ b2_f,
        const float* __restrict__ Q_ws, const float* __restrict__ wa_f,
        const int* __restrict__ flag,
        float* __restrict__ bot, void* __restrict__ dout) {
    alignas(16) __shared__ float lds_h[4][EPW][128];
    alignas(16) __shared__ float lds_hr[4][EPW][128];
    alignas(16) __shared__ float lds_hs[4][EPW][128];
    int wv = threadIdx.x >> 6, lane = threadIdx.x & 63;
    int f = *flag;
    int nwaves = gridDim.x * 4;
    const int ngroups = N_EDGE / EPW;
    float b20 = b2_f[2 * lane], b21 = b2_f[2 * lane + 1];
    float wa = wa_f[lane];
    for (int g = blockIdx.x * 4 + wv; g < ngroups; g += nwaves) {
        int base = g * EPW;
        int rel[EPW], sub[EPW], obj[EPW], qi[EPW], tim[EPW];
#pragma unroll
        for (int e = 0; e < EPW; e++) {
            const int* ep = edges + (base + e) * 7;
            qi[e] = ep[0]; rel[e] = ep[2]; sub[e] = ep[4];
            obj[e] = ep[5]; tim[e] = ep[6];
        }
        float hs0[EPW], hs1[EPW];
#pragma unroll
        for (int e = 0; e < EPW; e++) {
            const float2* ar = (const float2*)(A_rel + rel[e] * 128);
            const float2* at = (const float2*)(A_timeb + tim[e] * 128);
            float2 a = ar[lane], t = at[lane];
            lds_h[wv][e][2 * lane]     = lrelu(a.x + t.x);
            lds_h[wv][e][2 * lane + 1] = lrelu(a.y + t.y);
            if (f) {
                ushort2 hv = ((const ushort2*)((const bf16*)hidden + sub[e] * 128))[lane];
                hs0[e] = bfbits2f(hv.x); hs1[e] = bfbits2f(hv.y);
            } else {
                float2 hv = ((const float2*)((const float*)hidden + sub[e] * 128))[lane];
                hs0[e] = hv.x; hs1[e] = hv.y;
            }
            lds_hs[wv][e][2 * lane]     = hs0[e];
            lds_hs[wv][e][2 * lane + 1] = hs1[e];
        }
        float acc0[EPW], acc1[EPW];
#pragma unroll
        for (int e = 0; e < EPW; e++) { acc0[e] = b20; acc1[e] = b21; }
        const float4* w0p = (const float4*)(W2T + (2 * lane) * 128);
        const float4* w1p = (const float4*)(W2T + (2 * lane + 1) * 128);
        for (int k4 = 0; k4 < 32; k4++) {
            float4 w0 = w0p[k4], w1 = w1p[k4];
#pragma unroll
            for (int e = 0; e < EPW; e++) {
                float4 h = ((const float4*)lds_h[wv][e])[k4];
                acc0[e] = dot4(h, w0, acc0[e]);
                acc1[e] = dot4(h, w1, acc1[e]);
            }
        }
        float hr0[EPW], hr1[EPW];
#pragma unroll
        for (int e = 0; e < EPW; e++) {
            const float2* rp = (const float2*)(rela_f + rel[e] * 128);
            float2 rv = rp[lane];
            hr0[e] = lrelu(acc0[e]) + rv.x;
            hr1[e] = lrelu(acc1[e]) + rv.y;
            lds_hr[wv][e][2 * lane]     = hr0[e];
            lds_hr[wv][e][2 * lane + 1] = hr1[e];
        }
        float att[EPW];
#pragma unroll
        for (int e = 0; e < EPW; e++) att[e] = Q_ws[qi[e] * 64 + lane];
        const float4* wrp = (const float4*)(WrT + lane * 128);
        const float4* wsp = (const float4*)(WsT + lane * 128);
        for (int k4 = 0; k4 < 32; k4++) {
            float4 w = wrp[k4], w2 = wsp[k4];
#pragma unroll
            for (int e = 0; e < EPW; e++) {
                float4 hr4 = ((const float4*)lds_hr[wv][e])[k4];
                float4 hs4 = ((const float4*)lds_hs[wv][e])[k4];
                att[e] = dot4(hr4, w, att[e]);
                att[e] = dot4(hs4, w2, att[e]);
            }
        }
        float ea[EPW];
#pragma unroll
        for (int e = 0; e < EPW; e++) {
            float a = lrelu(att[e]) * wa;
            a += __shfl_xor(a, 32); a += __shfl_xor(a, 16); a += __shfl_xor(a, 8);
            a += __shfl_xor(a, 4);  a += __shfl_xor(a, 2);  a += __shfl_xor(a, 1);
            ea[e] = __expf(a);
        }
#pragma unroll
        for (int e = 0; e < EPW; e++) {
            float v0 = ea[e] * (hs0[e] + hr0[e]);
            float v1 = ea[e] * (hs1[e] + hr1[e]);
            if (!f) {
                float* dst = (float*)dout + obj[e] * 128 + 2 * lane;
                unsafeAtomicAdd(dst,     v0);
                unsafeAtomicAdd(dst + 1, v1);
            } else {
                atom_pk_bf16((unsigned int*)dout + obj[e] * 64 + lane, v0, v1);
            }
            if (lane == 0) unsafeAtomicAdd(bot + obj[e], ea[e]);
        }
    }
}

// ---------- epilogue: out[n] = (up[n]/bot[n]) @ Wh ----------
// Wave-per-node, barrier-free: each wave stages its node row in a wave-private LDS row,
// lane j computes cols j and j+64 (conflict-free stride-1 wh reads, m broadcast).
// Summation order over k unchanged -> bit-identical to the block-barrier version.
__global__ __launch_bounds__(256) void k_out(const float* __restrict__ up,
                      const float* __restrict__ bot,
                      const float* __restrict__ Wh_f, void* __restrict__ dout,
                      const int* __restrict__ flag, int tier_full) {
    __shared__ float wh[123][128];   // 61.5 KB: rows 0..122 cached; 123..127 from L2
    __shared__ float m[4][128];      // wave-private staging rows
    int tid = threadIdx.x;
    int wv = tid >> 6, lane = tid & 63;
    int f = *flag;
    for (int i = tid; i < 123 * 128; i += 256) ((float*)wh)[i] = Wh_f[i];
    __syncthreads();
    int nwv = gridDim.x * 4;
    for (int n = blockIdx.x * 4 + wv; n < N_NODE; n += nwv) {
        float inv = 1.f / (bot[n] + 1e-5f);
        float num0, num1;   // cols lane, lane+64
        if (tier_full) {
            num0 = up[(size_t)n * 128 + lane];
            num1 = up[(size_t)n * 128 + 64 + lane];
        } else if (!f) {
            num0 = ((const float*)dout)[(size_t)n * 128 + lane];
            num1 = ((const float*)dout)[(size_t)n * 128 + 64 + lane];
        } else {
            unsigned int wlo = ((const unsigned int*)dout)[(size_t)n * 64 + (lane >> 1)];
            unsigned int whi = ((const unsigned int*)dout)[(size_t)n * 64 + 32 + (lane >> 1)];
            num0 = bfbits2f((unsigned short)((lane & 1) ? (wlo >> 16) : (wlo & 0xffffu)));
            num1 = bfbits2f((unsigned short)((lane & 1) ? (whi >> 16) : (whi & 0xffffu)));
        }
        m[wv][lane]      = num0 * inv;
        m[wv][64 + lane] = num1 * inv;
        // wave-internal LDS write->read: compiler-inserted lgkmcnt ordering, no barrier
        float acc0 = 0.f, acc1 = 0.f;
#pragma unroll 4
        for (int k = 0; k < 123; k++) {
            float mv = m[wv][k];
            acc0 = fmaf(mv, wh[k][lane], acc0);
            acc1 = fmaf(mv, wh[k][64 + lane], acc1);
        }
#pragma unroll
        for (int k = 123; k < 128; k++) {
            float mv = m[wv][k];
            acc0 = fmaf(mv, Wh_f[k * 128 + lane], acc0);
            acc1 = fmaf(mv, Wh_f[k * 128 + 64 + lane], acc1);
        }
        if (f) {
            ((bf16*)dout)[(size_t)n * 128 + lane]      = __float2bfloat16(acc0);
            ((bf16*)dout)[(size_t)n * 128 + 64 + lane] = __float2bfloat16(acc1);
        } else {
            ((float*)dout)[(size_t)n * 128 + lane]      = acc0;
            ((float*)dout)[(size_t)n * 128 + 64 + lane] = acc1;
        }
    }
}

// ---------- launcher ----------
extern "C" void kernel_launch(void* const* d_in, const int* in_sizes, int n_in,
                              void* d_out, int out_size, void* d_ws, size_t ws_size,
                              hipStream_t stream) {
    const void* hidden = d_in[0];
    const void* rela   = d_in[1];
    const void* pe     = d_in[2];
    const void* W1     = d_in[3];
    const void* b1     = d_in[4];
    const void* W2     = d_in[5];
    const void* b2     = d_in[6];
    const void* Ws     = d_in[7];
    const void* Wr     = d_in[8];
    const void* Wqr    = d_in[9];
    const void* bqr    = d_in[10];
    const void* walpha = d_in[11];
    const void* Wh     = d_in[12];
    const int* q_rel   = (const int*)d_in[13];
    const int* edges   = (const int*)d_in[14];

    float* ws = (float*)d_ws;
    size_t off = 0;
    int*   flag    = (int*)(ws + off); off += 4;
    float* pool    = ws + off;
    float* rela_f  = pool;
    float* pe_f    = rela_f + SEG_RELA;
    float* W1_f    = pe_f + SEG_PE;
    float* b1_f    = W1_f + SEG_W1;
    float* W2T_f   = b1_f + SEG_B1;
    float* b2_f    = W2T_f + SEG_W2T;
    float* WsT_f   = b2_f + SEG_B2;
    float* Ws_f    = WsT_f + SEG_WST;
    float* WrT_f   = Ws_f + SEG_WS;
    float* WqrT_f  = WrT_f + SEG_WRT;
    float* bqr_f   = WqrT_f + SEG_WQRT;
    float* wa_f    = bqr_f + SEG_BQR;
    float* Wh_f    = wa_f + SEG_WA;
    off += POOL_TOTAL;
    float* A_rel   = ws + off; off += 401 * 128;
    float* A_timeb = ws + off; off += 1000 * 128;
    float* Q_ws    = ws + off; off += N_QUERY * 64;
    float* bot     = ws + off; off += N_NODE;
    short* W2pk    = (short*)(ws + off); off += 8192;
    short* Wrpk    = (short*)(ws + off); off += 4096;
    unsigned short* relcat = (unsigned short*)(ws + off); off += 401 * 128;   // 401*256 bf16
    unsigned short* atimb  = (unsigned short*)(ws + off); off += 1000 * 64;   // 1000*128 bf16
    unsigned short* S_b    = (unsigned short*)(ws + off); off += (size_t)N_NODE * 32; // 50000*64 bf16
    float* up      = ws + off; off += (size_t)N_NODE * 128;
    int*   perm    = (int*)(ws + off); off += N_EDGE;
    int*   cnt     = (int*)(ws + off); off += N_NODE + 32;
    int*   cur     = (int*)(ws + off); off += N_NODE + 32;
    int*   tot     = (int*)(ws + off); off += 64;
    size_t full_floats = off;   // ~9.46M floats = 37.85 MB (proven ws >= 39.6 MB)

    int tier_full = (ws_size >= full_floats * sizeof(float)) ? 1 : 0;

    if (tier_full) {
        // DMA memset nodes: flag-independent, cheaper than a zeroing kernel
        hipMemsetAsync(bot, 0, (size_t)N_NODE * sizeof(float), stream);
        hipMemsetAsync(up,  0, (size_t)N_NODE * 128 * sizeof(float), stream);
        hipMemsetAsync(cnt, 0, (size_t)(N_NODE + 32) * sizeof(int), stream);
    }

    k_detect<<<1, 1, 0, stream>>>((const unsigned int*)pe, flag);
    if (!tier_full) {
        k_zero<<<2048, 256, 0, stream>>>((unsigned int*)d_out, out_size, flag, bot, up, cnt, 0);
    }
    k_convert<<<(POOL_TOTAL + 255) / 256, 256, 0, stream>>>(
        rela, pe, W1, b1, W2, b2, Ws, Wr, Wqr, bqr, walpha, Wh, flag, pool);
    k_arel<<<401, 128, 0, stream>>>(rela_f, W1_f, A_rel, relcat);
    k_atime<<<1000, 128, 0, stream>>>(pe_f, W1_f, b1_f, A_timeb, atimb);
    k_qws<<<N_QUERY / 4, 256, 0, stream>>>(rela_f, q_rel, bqr_f, WqrT_f, Q_ws);

    if (tier_full) {
        k_pack<<<96, 256, 0, stream>>>(W2T_f, WrT_f, W2pk, Wrpk);
        k_snode<<<1024, 256, 0, stream>>>(hidden, Ws_f, flag, S_b);
        k_hist<<<1024, 256, 0, stream>>>(edges, cnt);
        k_scan1<<<49, 1024, 0, stream>>>(cnt, cur, tot);
        k_scan2<<<49, 1024, 0, stream>>>(tot, cur);
        k_scat<<<1024, 256, 0, stream>>>(edges, cur, perm);
        // 512 blocks = 2 blocks/CU x 256 CU at VGPR=176: whole grid resident in one batch
        k_edge_s<<<512, 256, 0, stream>>>(edges, perm, hidden, relcat, atimb, W2pk, Wrpk,
                                          b2_f, S_b, Q_ws, wa_f, flag, up, bot);
    } else {
        k_edge_c<<<1536, 256, 0, stream>>>(edges, hidden, rela_f, A_rel, A_timeb,
                                           W2T_f, WrT_f, WsT_f, b2_f, Q_ws, wa_f,
                                           flag, bot, d_out);
    }

    k_out<<<500, 256, 0, stream>>>(up, bot, Wh_f, d_out, flag, tier_full);
}